// Round 8
// baseline (789.259 us; speedup 1.0000x reference)
//
#include <hip/hip_runtime.h>
#include <hip/hip_bf16.h>

typedef __attribute__((ext_vector_type(8))) short short8;
typedef __attribute__((ext_vector_type(4))) float f32x4;
typedef unsigned int uint32;

// async global->LDS, 16B per lane; LDS dest = uniform base + lane*16
#define GLD16(g, l) __builtin_amdgcn_global_load_lds( \
    (const __attribute__((address_space(1))) unsigned int*)(g), \
    (__attribute__((address_space(3))) unsigned int*)(l), 16, 0, 0)

// counted-vmcnt barriers (T4): loads stay in flight across the barrier
#define BAR_VM4()  asm volatile("s_waitcnt vmcnt(4)\ns_barrier" ::: "memory")
#define BAR_VM0()  asm volatile("s_waitcnt vmcnt(0)\ns_barrier" ::: "memory")
#define BAR_LGKM() asm volatile("s_waitcnt lgkmcnt(0)\ns_barrier" ::: "memory")

__device__ __forceinline__ float bfu(unsigned short u) {
    union { uint32 v; float f; } x; x.v = ((uint32)u) << 16; return x.f;
}
__device__ __forceinline__ void storev(float* p, float v) { *p = v; }
__device__ __forceinline__ void storev(__hip_bfloat16* p, float v) { *p = __float2bfloat16(v); }

// ============ transpose fp32 [K,N] -> bf16 [N,K] ============
__global__ __launch_bounds__(256) void transpose_bf16(
    const float* __restrict__ W, __hip_bfloat16* __restrict__ WT, int K, int N)
{
    __shared__ float tile[32][33];
    int k0 = blockIdx.x * 32, n0 = blockIdx.y * 32;
    int tx = threadIdx.x & 31, ty = threadIdx.x >> 5;   // 32 x 8
    #pragma unroll
    for (int i = 0; i < 32; i += 8)
        tile[ty + i][tx] = W[(size_t)(k0 + ty + i) * N + n0 + tx];
    __syncthreads();
    #pragma unroll
    for (int i = 0; i < 32; i += 8)
        WT[(size_t)(n0 + ty + i) * K + k0 + tx] = __float2bfloat16(tile[tx][ty + i]);
}

// ============ encoders ============
__global__ __launch_bounds__(256) void encode_nodes(
    const float* __restrict__ x, const float* __restrict__ Wn,
    const float* __restrict__ bn, __hip_bfloat16* __restrict__ h, int Nn)
{
    int idx = blockIdx.x * 256 + threadIdx.x;
    if (idx >= Nn * 512) return;
    int n = idx >> 9, c = idx & 511;
    float acc = bn[c];
    #pragma unroll
    for (int f = 0; f < 7; ++f) acc += x[n * 7 + f] * Wn[f * 512 + c];
    h[idx] = __float2bfloat16(fmaxf(acc, 0.f));
}

__global__ __launch_bounds__(256) void encode_edges(
    const float* __restrict__ eat, const float* __restrict__ We,
    const float* __restrict__ be, __hip_bfloat16* __restrict__ ea, int E)
{
    int idx = blockIdx.x * 256 + threadIdx.x;
    if (idx >= E * 512) return;
    int e = idx >> 9, c = idx & 511;
    float v = fmaf(eat[e * 2], We[c], fmaf(eat[e * 2 + 1], We[512 + c], be[c]));
    ea[idx] = __float2bfloat16(fmaxf(v, 0.f));
}

// ============ bf16 MFMA GEMM: 2-phase dbuf + counted vmcnt (T3/T4) ============
template <typename OutT, bool HAS_BIAS>
__global__ __launch_bounds__(256) void mfma_gemm(
    const __hip_bfloat16* __restrict__ A, int lda, long az,
    const __hip_bfloat16* __restrict__ BT, int ldb, long bz,
    const float* __restrict__ bias,
    OutT* __restrict__ C, int ldc, long cz, int M, int K)
{
    __shared__ uint4 As4[1024];   // 2 x 8 KB double buffer
    __shared__ uint4 Bs4[1024];
    A  += (long)blockIdx.z * az;
    BT += (long)blockIdx.z * bz;
    C  += (long)blockIdx.z * cz;
    const int t = threadIdx.x, lane = t & 63, w = t >> 6;
    const int wr = (w >> 1) * 64, wc = (w & 1) * 64;
    const int col0 = blockIdx.x * 128, row0 = blockIdx.y * 128;  // x = col tile (fast)
    const int lr = lane & 15, lg = lane >> 4;
    const int r0 = w * 16 + (lane >> 2);                     // staging row, seg w
    const int ksw = ((lane & 3) ^ ((lane >> 3) & 3)) * 8;    // swizzled k-chunk (elems)
    const int rsw = (lg ^ ((lr >> 1) & 3)) << 4;             // read-side swizzle (bytes)

    const __hip_bfloat16* Ap0 = A + (size_t)(row0 + r0) * lda + ksw;
    const __hip_bfloat16* Ap1 = A + (size_t)(row0 + r0 + 64) * lda + ksw;
    const __hip_bfloat16* Bp0 = BT + (size_t)(col0 + r0) * ldb + ksw;
    const __hip_bfloat16* Bp1 = BT + (size_t)(col0 + r0 + 64) * ldb + ksw;

    f32x4 acc[4][4];
    #pragma unroll
    for (int m = 0; m < 4; ++m)
        #pragma unroll
        for (int n = 0; n < 4; ++n) acc[m][n] = 0.f;

    // prologue: stage k=0 into buf0
    GLD16(Ap0, As4 + w * 64);
    GLD16(Ap1, As4 + (w + 4) * 64);
    GLD16(Bp0, Bs4 + w * 64);
    GLD16(Bp1, Bs4 + (w + 4) * 64);

    int cur = 0;
    for (int k0 = 0; k0 < K; k0 += 32, cur ^= 1) {
        int nk = k0 + 32;
        if (nk < K) {                       // stage next tile into other buffer
            uint4* a = As4 + (cur ^ 1) * 512;
            uint4* b = Bs4 + (cur ^ 1) * 512;
            GLD16(Ap0 + nk, a + w * 64);
            GLD16(Ap1 + nk, a + (w + 4) * 64);
            GLD16(Bp0 + nk, b + w * 64);
            GLD16(Bp1 + nk, b + (w + 4) * 64);
            BAR_VM4();                      // wait only current tile's 4 loads
        } else {
            BAR_VM0();
        }
        const char* AsB = (const char*)(As4 + cur * 512);
        const char* BsB = (const char*)(Bs4 + cur * 512);
        short8 af[4], bfrag[4];
        #pragma unroll
        for (int m = 0; m < 4; ++m)
            af[m] = *(const short8*)(AsB + (wr + m * 16 + lr) * 64 + rsw);
        #pragma unroll
        for (int n = 0; n < 4; ++n)
            bfrag[n] = *(const short8*)(BsB + (wc + n * 16 + lr) * 64 + rsw);
        BAR_LGKM();                         // reads landed; buffer reusable
        __builtin_amdgcn_s_setprio(1);
        #pragma unroll
        for (int m = 0; m < 4; ++m)
            #pragma unroll
            for (int n = 0; n < 4; ++n)
                acc[m][n] = __builtin_amdgcn_mfma_f32_16x16x32_bf16(af[m], bfrag[n], acc[m][n], 0, 0, 0);
        __builtin_amdgcn_s_setprio(0);
    }

    #pragma unroll
    for (int m = 0; m < 4; ++m) {
        #pragma unroll
        for (int r = 0; r < 4; ++r) {
            int gr = row0 + wr + m * 16 + lg * 4 + r;
            if (gr >= M) continue;
            #pragma unroll
            for (int n = 0; n < 4; ++n) {
                int gc = col0 + wc + n * 16 + lr;
                float v = acc[m][n][r];
                if (HAS_BIAS) v += bias[gc];
                storev(&C[(size_t)gr * ldc + gc], v);
            }
        }
    }
}

// ============ edge GEMM + fused logits (2-phase dbuf K-loop and strips) ========
__global__ __launch_bounds__(256) void edge_mfma_logits(
    const __hip_bfloat16* __restrict__ ea,    // [EP,512]
    const __hip_bfloat16* __restrict__ WleT,  // [2048,512]
    const __hip_bfloat16* __restrict__ XL,
    const __hip_bfloat16* __restrict__ XR,
    const int* __restrict__ ei,
    const float* __restrict__ att,
    float* __restrict__ logits,               // [E,4] pre-zeroed, atomic partial
    int E)
{
    __shared__ uint4 As4[1024];
    __shared__ uint4 Bs4[1024];
    __shared__ int srcs[128], dsts[128];
    const int t = threadIdx.x, lane = t & 63, w = t >> 6;
    const int wr = (w >> 1) * 64, wc = (w & 1) * 64;
    const int col0 = blockIdx.x * 128, row0 = blockIdx.y * 128;  // x = col tile (fast)
    const int lr = lane & 15, lg = lane >> 4;
    const int r0 = w * 16 + (lane >> 2);
    const int ksw = ((lane & 3) ^ ((lane >> 3) & 3)) * 8;
    const int rsw = (lg ^ ((lr >> 1) & 3)) << 4;

    const __hip_bfloat16* Ap0 = ea + (size_t)(row0 + r0) * 512 + ksw;
    const __hip_bfloat16* Ap1 = ea + (size_t)(row0 + r0 + 64) * 512 + ksw;
    const __hip_bfloat16* Bp0 = WleT + (size_t)(col0 + r0) * 512 + ksw;
    const __hip_bfloat16* Bp1 = WleT + (size_t)(col0 + r0 + 64) * 512 + ksw;

    // prologue: stage k=0 into buf0
    GLD16(Ap0, As4 + w * 64);
    GLD16(Ap1, As4 + (w + 4) * 64);
    GLD16(Bp0, Bs4 + w * 64);
    GLD16(Bp1, Bs4 + (w + 4) * 64);

    if (t < 128) {
        int ge = row0 + t;
        bool ok = ge < E;
        srcs[t] = ok ? ei[ge] : 0;
        dsts[t] = ok ? ei[E + ge] : 0;
    }
    BAR_LGKM();   // srcs/dsts visible; staged loads remain in flight

    f32x4 acc[4][4];
    #pragma unroll
    for (int m = 0; m < 4; ++m)
        #pragma unroll
        for (int n = 0; n < 4; ++n) acc[m][n] = 0.f;

    int cur = 0;
    for (int k0 = 0; k0 < 512; k0 += 32, cur ^= 1) {
        int nk = k0 + 32;
        if (nk < 512) {
            uint4* a = As4 + (cur ^ 1) * 512;
            uint4* b = Bs4 + (cur ^ 1) * 512;
            GLD16(Ap0 + nk, a + w * 64);
            GLD16(Ap1 + nk, a + (w + 4) * 64);
            GLD16(Bp0 + nk, b + w * 64);
            GLD16(Bp1 + nk, b + (w + 4) * 64);
            BAR_VM4();
        } else {
            BAR_VM0();
        }
        const char* AsB = (const char*)(As4 + cur * 512);
        const char* BsB = (const char*)(Bs4 + cur * 512);
        short8 af[4], bfrag[4];
        #pragma unroll
        for (int m = 0; m < 4; ++m)
            af[m] = *(const short8*)(AsB + (wr + m * 16 + lr) * 64 + rsw);
        #pragma unroll
        for (int n = 0; n < 4; ++n)
            bfrag[n] = *(const short8*)(BsB + (wc + n * 16 + lr) * 64 + rsw);
        BAR_LGKM();
        __builtin_amdgcn_s_setprio(1);
        #pragma unroll
        for (int m = 0; m < 4; ++m)
            #pragma unroll
            for (int n = 0; n < 4; ++n)
                acc[m][n] = __builtin_amdgcn_mfma_f32_16x16x32_bf16(af[m], bfrag[n], acc[m][n], 0, 0, 0);
        __builtin_amdgcn_s_setprio(0);
    }

    // ---- logits epilogue: XL/XR 32-col strips, double-buffered (T14-style) ----
    const int hh = col0 >> 9;
    float attv[4];
    #pragma unroll
    for (int n = 0; n < 4; ++n)
        attv[n] = att[hh * 512 + ((col0 + wc + n * 16 + lr) & 511)];
    float part[4][4];
    #pragma unroll
    for (int m = 0; m < 4; ++m)
        #pragma unroll
        for (int r = 0; r < 4; ++r) part[m][r] = 0.f;

    const int prt = (lane & 3) * 8;   // 8-elem sub-chunk within 32-col strip
    const int s0 = srcs[r0], s1 = srcs[r0 + 64];
    const int d0 = dsts[r0], d1 = dsts[r0 + 64];

    // stage strip 0 into buf0 (K-loop's last read was buf1; buf0 drained)
    {
        int cc = col0;
        GLD16(XL + (size_t)s0 * 2048 + cc + prt, As4 + w * 64);
        GLD16(XL + (size_t)s1 * 2048 + cc + prt, As4 + (w + 4) * 64);
        GLD16(XR + (size_t)d0 * 2048 + cc + prt, Bs4 + w * 64);
        GLD16(XR + (size_t)d1 * 2048 + cc + prt, Bs4 + (w + 4) * 64);
    }
    #pragma unroll
    for (int ch = 0; ch < 4; ++ch) {
        if (ch < 3) {
            uint4* a = As4 + ((ch + 1) & 1) * 512;
            uint4* b = Bs4 + ((ch + 1) & 1) * 512;
            int cc = col0 + (ch + 1) * 32;
            GLD16(XL + (size_t)s0 * 2048 + cc + prt, a + w * 64);
            GLD16(XL + (size_t)s1 * 2048 + cc + prt, a + (w + 4) * 64);
            GLD16(XR + (size_t)d0 * 2048 + cc + prt, b + w * 64);
            GLD16(XR + (size_t)d1 * 2048 + cc + prt, b + (w + 4) * 64);
            BAR_VM4();
        } else {
            BAR_VM0();
        }
        const char* AsB = (const char*)(As4 + (ch & 1) * 512);
        const char* BsB = (const char*)(Bs4 + (ch & 1) * 512);
        #pragma unroll
        for (int n = 0; n < 4; ++n) {
            if (((wc + n * 16) >> 5) != ch) continue;
            int colin = ((n & 1) << 4) + lr;
            #pragma unroll
            for (int m = 0; m < 4; ++m) {
                #pragma unroll
                for (int r = 0; r < 4; ++r) {
                    int row = wr + m * 16 + lg * 4 + r;
                    float xl = bfu(*(const unsigned short*)(AsB + row * 64 + colin * 2));
                    float xr = bfu(*(const unsigned short*)(BsB + row * 64 + colin * 2));
                    float mv = acc[m][n][r] + xl + xr;
                    part[m][r] += attv[n] * ((mv > 0.f) ? mv : 0.2f * mv);
                }
            }
        }
        BAR_LGKM();   // strip reads landed; buffer reusable
    }
    #pragma unroll
    for (int m = 0; m < 4; ++m) {
        #pragma unroll
        for (int r = 0; r < 4; ++r) {
            float p = part[m][r];
            p += __shfl_xor(p, 1); p += __shfl_xor(p, 2);
            p += __shfl_xor(p, 4); p += __shfl_xor(p, 8);
            int ge = row0 + wr + m * 16 + lg * 4 + r;
            if (lr == 0 && ge < E) atomicAdd(&logits[ge * 4 + hh], p);
        }
    }
}

// ============ counting sort of edges by dst ============
__global__ __launch_bounds__(256) void count_dst(
    const int* __restrict__ ei, int* __restrict__ cnt, int E)
{
    int e = blockIdx.x * 256 + threadIdx.x;
    if (e < E) atomicAdd(&cnt[ei[E + e]], 1);
}

// single-block hierarchical exclusive scan: offs[0..N], offs[N] = total
__global__ __launch_bounds__(1024) void scan_kernel(
    const int* __restrict__ cnt, int* __restrict__ offs, int N)
{
    __shared__ int wsum[16];
    __shared__ int stot;
    __shared__ int carry_s;
    int t = threadIdx.x, lane = t & 63, w = t >> 6;
    if (t == 0) carry_s = 0;
    __syncthreads();
    for (int base = 0; base < N; base += 1024) {
        int v = (base + t < N) ? cnt[base + t] : 0;
        int x = v;
        #pragma unroll
        for (int off = 1; off < 64; off <<= 1) {
            int y = __shfl_up(x, off);
            if (lane >= off) x += y;
        }
        if (lane == 63) wsum[w] = x;
        __syncthreads();                       // (A) wsum ready
        if (w == 0 && lane < 16) {
            int v0 = wsum[lane];
            int s = v0;
            #pragma unroll
            for (int off = 1; off < 16; off <<= 1) {
                int y = __shfl_up(s, off);
                if (lane >= off) s += y;
            }
            wsum[lane] = s - v0;               // exclusive prefix of wave sums
            if (lane == 15) stot = s;          // chunk total
        }
        __syncthreads();                       // (B) wsum/stot ready
        if (base + t < N) offs[base + t] = carry_s + wsum[w] + x - v;
        __syncthreads();                       // (C) carry_s reads done
        if (t == 0) carry_s += stot;
    }
    __syncthreads();
    if (t == 0) offs[N] = carry_s;
}

__global__ __launch_bounds__(256) void fill_elist(
    const int* __restrict__ ei, const int* __restrict__ offs,
    int* __restrict__ cnt2, int* __restrict__ elist, int E)
{
    int e = blockIdx.x * 256 + threadIdx.x;
    if (e >= E) return;
    int d = ei[E + e];
    int p = offs[d] + atomicAdd(&cnt2[d], 1);
    elist[p] = e;
}

// ============ fused: softmax + gather-aggregate(Y) + relu + GEMV + sigmoid =====
// one wave per dst node; 4 dsts per 256-thread block
__global__ __launch_bounds__(256) void gat_out(
    const __hip_bfloat16* __restrict__ Y,     // [N,4,512] bf16
    const int* __restrict__ ei,
    const int* __restrict__ elist, const int* __restrict__ offs,
    const float* __restrict__ logits,
    const float* __restrict__ bias2,
    const float* __restrict__ Wd2,            // [512,6]
    const float* __restrict__ bd2,
    float* __restrict__ out, int N, int E)
{
    __shared__ float wds[512 * 6];   // 12 KB
    int t = threadIdx.x;
    for (int i = t; i < 512 * 6; i += 256) wds[i] = Wd2[i];
    __syncthreads();
    int w = t >> 6, lane = t & 63;
    int dst = blockIdx.x * 4 + w;
    if (dst >= N) return;
    int s = offs[dst], cntE = offs[dst + 1] - s;

    float den[4] = {0.f, 0.f, 0.f, 0.f};
    for (int i = 0; i < cntE; ++i) {
        int e = elist[s + i];
        #pragma unroll
        for (int h = 0; h < 4; ++h) den[h] += expf(logits[e * 4 + h]);
    }
    float acc[8] = {0.f, 0.f, 0.f, 0.f, 0.f, 0.f, 0.f, 0.f};
    for (int i = 0; i < cntE; ++i) {
        int e = elist[s + i];
        int src = ei[e];
        #pragma unroll
        for (int h = 0; h < 4; ++h) {
            float al = expf(logits[e * 4 + h]) / (den[h] + 1e-16f);
            uint4 q = *(const uint4*)((const unsigned short*)Y
                        + ((size_t)src * 4 + h) * 512 + lane * 8);
            acc[0] += al * bfu((unsigned short)(q.x & 0xffff));
            acc[1] += al * bfu((unsigned short)(q.x >> 16));
            acc[2] += al * bfu((unsigned short)(q.y & 0xffff));
            acc[3] += al * bfu((unsigned short)(q.y >> 16));
            acc[4] += al * bfu((unsigned short)(q.z & 0xffff));
            acc[5] += al * bfu((unsigned short)(q.z >> 16));
            acc[6] += al * bfu((unsigned short)(q.w & 0xffff));
            acc[7] += al * bfu((unsigned short)(q.w >> 16));
        }
    }
    float p[6] = {0.f, 0.f, 0.f, 0.f, 0.f, 0.f};
    #pragma unroll
    for (int j = 0; j < 8; ++j) {
        int c = lane * 8 + j;
        float u = fmaxf(acc[j] + bias2[c], 0.f);
        #pragma unroll
        for (int jj = 0; jj < 6; ++jj) p[jj] += u * wds[c * 6 + jj];
    }
    #pragma unroll
    for (int off = 32; off; off >>= 1)
        #pragma unroll
        for (int jj = 0; jj < 6; ++jj) p[jj] += __shfl_down(p[jj], off);
    if (lane == 0) {
        #pragma unroll
        for (int jj = 0; jj < 6; ++jj)
            out[(size_t)dst * 6 + jj] = 1.f / (1.f + expf(-(p[jj] + bd2[jj])));
    }
}

// ============ bias2 = b_d1 + conv_bias @ W_d1 ============
__global__ __launch_bounds__(256) void bias2_kernel(
    const float* __restrict__ bd1, const float* __restrict__ cb,
    const float* __restrict__ Wd1, float* __restrict__ bias2)
{
    int j = blockIdx.x * 256 + threadIdx.x;
    if (j >= 512) return;
    float acc = bd1[j];
    for (int k = 0; k < 2048; ++k) acc += cb[k] * Wd1[(size_t)k * 512 + j];
    bias2[j] = acc;
}

extern "C" void kernel_launch(void* const* d_in, const int* in_sizes, int n_in,
                              void* d_out, int out_size, void* d_ws, size_t ws_size,
                              hipStream_t stream)
{
    const float* x         = (const float*)d_in[0];
    const float* edge_attr = (const float*)d_in[1];
    const int*   ei        = (const int*)d_in[2];
    const float* W_node = (const float*)d_in[3],  *b_node = (const float*)d_in[4];
    const float* W_edge = (const float*)d_in[5],  *b_edge = (const float*)d_in[6];
    const float* W_l    = (const float*)d_in[7],  *b_l    = (const float*)d_in[8];
    const float* W_r    = (const float*)d_in[9],  *b_r    = (const float*)d_in[10];
    const float* W_le   = (const float*)d_in[11];
    const float* att    = (const float*)d_in[12];
    const float* conv_bias = (const float*)d_in[13];
    const float* W_d1   = (const float*)d_in[14], *b_d1 = (const float*)d_in[15];
    const float* W_d2   = (const float*)d_in[16], *b_d2 = (const float*)d_in[17];
    float* out = (float*)d_out;

    const int N = in_sizes[0] / 7;   // 25000
    const int E = in_sizes[1] / 2;   // 50000
    const int MP = (N + 127) & ~127; // padded rows (unguarded async A-reads)
    const int EP = (E + 127) & ~127;

    // ---- workspace layout (~267 MB) ----
    char* ws = (char*)d_ws;
    const size_t szR0 = (size_t)EP * 512 * 2;     // h bf16[MP,512] then ea bf16[EP,512]
    const size_t szX  = (size_t)MP * 2048 * 2;
    const size_t szW  = (size_t)2048 * 512 * 2;
    const size_t szlg = (size_t)E * 4 * 4;
    const size_t szI  = (((size_t)(N + 1) * 4) + 15) & ~(size_t)15;
    const size_t o_XL = szR0;
    const size_t o_XR = o_XL + szX;
    const size_t o_W  = o_XR + szX;
    const size_t o_lg = o_W + 4 * szW;
    const size_t o_b2 = o_lg + szlg;
    const size_t o_cnt = o_b2 + 2048;
    const size_t o_cnt2 = o_cnt + szI;
    const size_t o_off = o_cnt2 + szI;
    const size_t o_el = o_off + szI;
    const size_t need = o_el + (size_t)E * 4;
    if (ws_size < need) return;   // clean diagnostic failure if ws too small

    __hip_bfloat16* h   = (__hip_bfloat16*)ws;
    __hip_bfloat16* ea  = (__hip_bfloat16*)ws;
    __hip_bfloat16* XL  = (__hip_bfloat16*)(ws + o_XL);
    __hip_bfloat16* XR  = (__hip_bfloat16*)(ws + o_XR);
    __hip_bfloat16* Y   = XR;                       // overlays XR after logits
    __hip_bfloat16* WlT = (__hip_bfloat16*)(ws + o_W);
    __hip_bfloat16* WrT = WlT + szW / 2;
    __hip_bfloat16* WleT= WrT + szW / 2;
    __hip_bfloat16* Wd1T= WleT + szW / 2;
    float* logits = (float*)(ws + o_lg);
    float* bias2  = (float*)(ws + o_b2);
    int* cnt   = (int*)(ws + o_cnt);
    int* cnt2  = (int*)(ws + o_cnt2);
    int* offs  = (int*)(ws + o_off);
    int* elist = (int*)(ws + o_el);

    hipMemsetAsync(logits, 0, szlg, stream);
    hipMemsetAsync(cnt, 0, szI, stream);
    hipMemsetAsync(cnt2, 0, szI, stream);

    // weight prep: [K,N] fp32 -> [N,K] bf16
    dim3 gT(512 / 32, 2048 / 32);
    transpose_bf16<<<gT, 256, 0, stream>>>(W_l,  WlT, 512, 2048);
    transpose_bf16<<<gT, 256, 0, stream>>>(W_r,  WrT, 512, 2048);
    transpose_bf16<<<gT, 256, 0, stream>>>(W_le, WleT, 512, 2048);
    dim3 gT2(2048 / 32, 512 / 32);
    transpose_bf16<<<gT2, 256, 0, stream>>>(W_d1, Wd1T, 2048, 512);
    bias2_kernel<<<2, 256, 0, stream>>>(b_d1, conv_bias, W_d1, bias2);

    // counting sort of edges by dst (only needs ei)
    count_dst<<<(E + 255) / 256, 256, 0, stream>>>(ei, cnt, E);
    scan_kernel<<<1, 1024, 0, stream>>>(cnt, offs, N);
    fill_elist<<<(E + 255) / 256, 256, 0, stream>>>(ei, offs, cnt2, elist, E);

    encode_nodes<<<(N * 512 + 255) / 256, 256, 0, stream>>>(x, W_node, b_node, h, N);

    const int MB = MP / 128;
    dim3 gNode(2048 / 128, MB);                       // x = col tile (fast)
    mfma_gemm<__hip_bfloat16, true><<<gNode, 256, 0, stream>>>(
        h, 512, 0, WlT, 512, 0, b_l, XL, 2048, 0, N, 512);
    mfma_gemm<__hip_bfloat16, true><<<gNode, 256, 0, stream>>>(
        h, 512, 0, WrT, 512, 0, b_r, XR, 2048, 0, N, 512);

    // h dead -> region0 becomes ea
    encode_edges<<<(E * 512 + 255) / 256, 256, 0, stream>>>(edge_attr, W_edge, b_edge, ea, E);

    dim3 gE(16, EP / 128);                            // x = col tile (fast)
    edge_mfma_logits<<<gE, 256, 0, stream>>>(ea, WleT, XL, XR, ei, att, logits, E);

    // Y[n, hh*512+c] = XL[n, hh*512:] @ W_d1[hh*512:, :]  (block-diag, grid.z=4)
    dim3 gY(512 / 128, MB, 4);
    mfma_gemm<__hip_bfloat16, false><<<gY, 256, 0, stream>>>(
        XL, 2048, 512, Wd1T, 2048, 512, nullptr, Y, 2048, 512, N, 512);

    gat_out<<<(N + 3) / 4, 256, 0, stream>>>(Y, ei, elist, offs, logits,
                                             bias2, W_d2, b_d2, out, N, E);
}

// Round 9
// 781.156 us; speedup vs baseline: 1.0104x; 1.0104x over previous
//
#include <hip/hip_runtime.h>
#include <hip/hip_bf16.h>

typedef __attribute__((ext_vector_type(8))) short short8;
typedef __attribute__((ext_vector_type(4))) float f32x4;
typedef unsigned int uint32;

// async global->LDS, 16B per lane; LDS dest = uniform base + lane*16
#define GLD16(g, l) __builtin_amdgcn_global_load_lds( \
    (const __attribute__((address_space(1))) unsigned int*)(g), \
    (__attribute__((address_space(3))) unsigned int*)(l), 16, 0, 0)

__device__ __forceinline__ float bfu(unsigned short u) {
    union { uint32 v; float f; } x; x.v = ((uint32)u) << 16; return x.f;
}
__device__ __forceinline__ void storev(float* p, float v) { *p = v; }
__device__ __forceinline__ void storev(__hip_bfloat16* p, float v) { *p = __float2bfloat16(v); }

// ============ transpose fp32 [K,N] -> bf16 [N,K] ============
__global__ __launch_bounds__(256) void transpose_bf16(
    const float* __restrict__ W, __hip_bfloat16* __restrict__ WT, int K, int N)
{
    __shared__ float tile[32][33];
    int k0 = blockIdx.x * 32, n0 = blockIdx.y * 32;
    int tx = threadIdx.x & 31, ty = threadIdx.x >> 5;   // 32 x 8
    #pragma unroll
    for (int i = 0; i < 32; i += 8)
        tile[ty + i][tx] = W[(size_t)(k0 + ty + i) * N + n0 + tx];
    __syncthreads();
    #pragma unroll
    for (int i = 0; i < 32; i += 8)
        WT[(size_t)(n0 + ty + i) * K + k0 + tx] = __float2bfloat16(tile[tx][ty + i]);
}

// ============ encoders ============
__global__ __launch_bounds__(256) void encode_nodes(
    const float* __restrict__ x, const float* __restrict__ Wn,
    const float* __restrict__ bn, __hip_bfloat16* __restrict__ h, int Nn)
{
    int idx = blockIdx.x * 256 + threadIdx.x;
    if (idx >= Nn * 512) return;
    int n = idx >> 9, c = idx & 511;
    float acc = bn[c];
    #pragma unroll
    for (int f = 0; f < 7; ++f) acc += x[n * 7 + f] * Wn[f * 512 + c];
    h[idx] = __float2bfloat16(fmaxf(acc, 0.f));
}

// edge encoder writing rows in dst-sorted order: ea[p] = relu(f(edge_attr[elist[p]]))
__global__ __launch_bounds__(256) void encode_edges_sorted(
    const float* __restrict__ eat, const int* __restrict__ elist,
    const float* __restrict__ We, const float* __restrict__ be,
    __hip_bfloat16* __restrict__ ea, int E)
{
    int idx = blockIdx.x * 256 + threadIdx.x;
    if (idx >= E * 512) return;
    int p = idx >> 9, c = idx & 511;
    int e = elist[p];
    float v = fmaf(eat[e * 2], We[c], fmaf(eat[e * 2 + 1], We[512 + c], be[c]));
    ea[idx] = __float2bfloat16(fmaxf(v, 0.f));
}

// ============ bf16 MFMA GEMM (single-buffer core; x = col tile fast) ============
template <typename OutT, bool HAS_BIAS>
__global__ __launch_bounds__(256) void mfma_gemm(
    const __hip_bfloat16* __restrict__ A, int lda, long az,
    const __hip_bfloat16* __restrict__ BT, int ldb, long bz,
    const float* __restrict__ bias, long biasz,
    OutT* __restrict__ C, int ldc, long cz, int M, int K)
{
    __shared__ uint4 As4[512];   // 8 KB
    __shared__ uint4 Bs4[512];
    A  += (long)blockIdx.z * az;
    BT += (long)blockIdx.z * bz;
    C  += (long)blockIdx.z * cz;
    if (HAS_BIAS) bias += (long)blockIdx.z * biasz;
    const int t = threadIdx.x, lane = t & 63, w = t >> 6;
    const int wr = (w >> 1) * 64, wc = (w & 1) * 64;
    const int col0 = blockIdx.x * 128, row0 = blockIdx.y * 128;  // x = col tile (fast)
    const int lr = lane & 15, lg = lane >> 4;
    const int r0 = w * 16 + (lane >> 2);                     // staging row, seg w
    const int ksw = ((lane & 3) ^ ((lane >> 3) & 3)) * 8;    // swizzled k-chunk (elems)
    const int rsw = (lg ^ ((lr >> 1) & 3)) << 4;             // read-side swizzle (bytes)

    const __hip_bfloat16* Ap0 = A + (size_t)(row0 + r0) * lda + ksw;
    const __hip_bfloat16* Ap1 = A + (size_t)(row0 + r0 + 64) * lda + ksw;
    const __hip_bfloat16* Bp0 = BT + (size_t)(col0 + r0) * ldb + ksw;
    const __hip_bfloat16* Bp1 = BT + (size_t)(col0 + r0 + 64) * ldb + ksw;
    char* AsB = (char*)As4; char* BsB = (char*)Bs4;
    uint4* la0 = As4 + w * 64;       uint4* la1 = As4 + (w + 4) * 64;
    uint4* lb0 = Bs4 + w * 64;       uint4* lb1 = Bs4 + (w + 4) * 64;

    f32x4 acc[4][4];
    #pragma unroll
    for (int m = 0; m < 4; ++m)
        #pragma unroll
        for (int n = 0; n < 4; ++n) acc[m][n] = 0.f;

    for (int k0 = 0; k0 < K; k0 += 32) {
        GLD16(Ap0 + k0, la0);
        GLD16(Ap1 + k0, la1);
        GLD16(Bp0 + k0, lb0);
        GLD16(Bp1 + k0, lb1);
        __syncthreads();
        short8 af[4], bfrag[4];
        #pragma unroll
        for (int m = 0; m < 4; ++m)
            af[m] = *(const short8*)(AsB + (wr + m * 16 + lr) * 64 + rsw);
        #pragma unroll
        for (int n = 0; n < 4; ++n)
            bfrag[n] = *(const short8*)(BsB + (wc + n * 16 + lr) * 64 + rsw);
        #pragma unroll
        for (int m = 0; m < 4; ++m)
            #pragma unroll
            for (int n = 0; n < 4; ++n)
                acc[m][n] = __builtin_amdgcn_mfma_f32_16x16x32_bf16(af[m], bfrag[n], acc[m][n], 0, 0, 0);
        __syncthreads();
    }

    #pragma unroll
    for (int m = 0; m < 4; ++m) {
        #pragma unroll
        for (int r = 0; r < 4; ++r) {
            int gr = row0 + wr + m * 16 + lg * 4 + r;
            if (gr >= M) continue;
            #pragma unroll
            for (int n = 0; n < 4; ++n) {
                int gc = col0 + wc + n * 16 + lr;
                float v = acc[m][n][r];
                if (HAS_BIAS) v += bias[gc];
                storev(&C[(size_t)gr * ldc + gc], v);
            }
        }
    }
}

// ============ edge GEMM + fused logits, sorted-edge space ============
__global__ __launch_bounds__(256) void edge_mfma_logits(
    const __hip_bfloat16* __restrict__ ea,    // [EP,512] (sorted rows)
    const __hip_bfloat16* __restrict__ WleT,  // [2048,512]
    const __hip_bfloat16* __restrict__ XL,
    const __hip_bfloat16* __restrict__ XR,
    const int* __restrict__ ssrc,             // [E] src per sorted pos
    const int* __restrict__ sdst,             // [E] dst per sorted pos
    const float* __restrict__ att,
    float* __restrict__ logits,               // [E,4] pre-zeroed, atomic partial
    int E)
{
    __shared__ uint4 As4[512];
    __shared__ uint4 Bs4[512];
    __shared__ int srcs[128], dsts[128];
    const int t = threadIdx.x, lane = t & 63, w = t >> 6;
    const int wr = (w >> 1) * 64, wc = (w & 1) * 64;
    const int col0 = blockIdx.x * 128, row0 = blockIdx.y * 128;  // x = col tile (fast)
    const int lr = lane & 15, lg = lane >> 4;
    const int r0 = w * 16 + (lane >> 2);
    const int ksw = ((lane & 3) ^ ((lane >> 3) & 3)) * 8;
    const int rsw = (lg ^ ((lr >> 1) & 3)) << 4;

    if (t < 128) {
        int ge = row0 + t;
        bool ok = ge < E;
        srcs[t] = ok ? ssrc[ge] : 0;
        dsts[t] = ok ? sdst[ge] : 0;
    }
    char* AsB = (char*)As4; char* BsB = (char*)Bs4;
    uint4* la0 = As4 + w * 64;       uint4* la1 = As4 + (w + 4) * 64;
    uint4* lb0 = Bs4 + w * 64;       uint4* lb1 = Bs4 + (w + 4) * 64;
    const __hip_bfloat16* Ap0 = ea + (size_t)(row0 + r0) * 512 + ksw;
    const __hip_bfloat16* Ap1 = ea + (size_t)(row0 + r0 + 64) * 512 + ksw;
    const __hip_bfloat16* Bp0 = WleT + (size_t)(col0 + r0) * 512 + ksw;
    const __hip_bfloat16* Bp1 = WleT + (size_t)(col0 + r0 + 64) * 512 + ksw;
    __syncthreads();

    f32x4 acc[4][4];
    #pragma unroll
    for (int m = 0; m < 4; ++m)
        #pragma unroll
        for (int n = 0; n < 4; ++n) acc[m][n] = 0.f;

    for (int k0 = 0; k0 < 512; k0 += 32) {
        GLD16(Ap0 + k0, la0);
        GLD16(Ap1 + k0, la1);
        GLD16(Bp0 + k0, lb0);
        GLD16(Bp1 + k0, lb1);
        __syncthreads();
        short8 af[4], bfrag[4];
        #pragma unroll
        for (int m = 0; m < 4; ++m)
            af[m] = *(const short8*)(AsB + (wr + m * 16 + lr) * 64 + rsw);
        #pragma unroll
        for (int n = 0; n < 4; ++n)
            bfrag[n] = *(const short8*)(BsB + (wc + n * 16 + lr) * 64 + rsw);
        #pragma unroll
        for (int m = 0; m < 4; ++m)
            #pragma unroll
            for (int n = 0; n < 4; ++n)
                acc[m][n] = __builtin_amdgcn_mfma_f32_16x16x32_bf16(af[m], bfrag[n], acc[m][n], 0, 0, 0);
        __syncthreads();
    }

    // ---- logits epilogue: stage XL/XR 32-col strips into reused As/Bs ----
    const int hh = col0 >> 9;
    float attv[4];
    #pragma unroll
    for (int n = 0; n < 4; ++n)
        attv[n] = att[hh * 512 + ((col0 + wc + n * 16 + lr) & 511)];
    float part[4][4];
    #pragma unroll
    for (int m = 0; m < 4; ++m)
        #pragma unroll
        for (int r = 0; r < 4; ++r) part[m][r] = 0.f;

    const int prt = (lane & 3) * 8;   // 8-elem sub-chunk within 32-col strip
    #pragma unroll
    for (int ch = 0; ch < 4; ++ch) {
        __syncthreads();   // previous strip/tile reads done
        int cc = col0 + ch * 32;
        GLD16(XL + (size_t)srcs[r0] * 2048 + cc + prt, la0);
        GLD16(XL + (size_t)srcs[r0 + 64] * 2048 + cc + prt, la1);
        GLD16(XR + (size_t)dsts[r0] * 2048 + cc + prt, lb0);
        GLD16(XR + (size_t)dsts[r0 + 64] * 2048 + cc + prt, lb1);
        __syncthreads();
        #pragma unroll
        for (int n = 0; n < 4; ++n) {
            if (((wc + n * 16) >> 5) != ch) continue;
            int colin = ((n & 1) << 4) + lr;
            #pragma unroll
            for (int m = 0; m < 4; ++m) {
                #pragma unroll
                for (int r = 0; r < 4; ++r) {
                    int row = wr + m * 16 + lg * 4 + r;
                    float xl = bfu(*(const unsigned short*)(AsB + row * 64 + colin * 2));
                    float xr = bfu(*(const unsigned short*)(BsB + row * 64 + colin * 2));
                    float mv = acc[m][n][r] + xl + xr;
                    part[m][r] += attv[n] * ((mv > 0.f) ? mv : 0.2f * mv);
                }
            }
        }
    }
    #pragma unroll
    for (int m = 0; m < 4; ++m) {
        #pragma unroll
        for (int r = 0; r < 4; ++r) {
            float p = part[m][r];
            p += __shfl_xor(p, 1); p += __shfl_xor(p, 2);
            p += __shfl_xor(p, 4); p += __shfl_xor(p, 8);
            int ge = row0 + wr + m * 16 + lg * 4 + r;
            if (lr == 0 && ge < E) atomicAdd(&logits[ge * 4 + hh], p);
        }
    }
}

// ============ counting sort of edges by dst ============
__global__ __launch_bounds__(256) void count_dst(
    const int* __restrict__ ei, int* __restrict__ cnt, int E)
{
    int e = blockIdx.x * 256 + threadIdx.x;
    if (e < E) atomicAdd(&cnt[ei[E + e]], 1);
}

// single-block hierarchical exclusive scan: offs[0..N], offs[N] = total
__global__ __launch_bounds__(1024) void scan_kernel(
    const int* __restrict__ cnt, int* __restrict__ offs, int N)
{
    __shared__ int wsum[16];
    __shared__ int stot;
    __shared__ int carry_s;
    int t = threadIdx.x, lane = t & 63, w = t >> 6;
    if (t == 0) carry_s = 0;
    __syncthreads();
    for (int base = 0; base < N; base += 1024) {
        int v = (base + t < N) ? cnt[base + t] : 0;
        int x = v;
        #pragma unroll
        for (int off = 1; off < 64; off <<= 1) {
            int y = __shfl_up(x, off);
            if (lane >= off) x += y;
        }
        if (lane == 63) wsum[w] = x;
        __syncthreads();                       // (A) wsum ready
        if (w == 0 && lane < 16) {
            int v0 = wsum[lane];
            int s = v0;
            #pragma unroll
            for (int off = 1; off < 16; off <<= 1) {
                int y = __shfl_up(s, off);
                if (lane >= off) s += y;
            }
            wsum[lane] = s - v0;               // exclusive prefix of wave sums
            if (lane == 15) stot = s;          // chunk total
        }
        __syncthreads();                       // (B) wsum/stot ready
        if (base + t < N) offs[base + t] = carry_s + wsum[w] + x - v;
        __syncthreads();                       // (C) carry_s reads done
        if (t == 0) carry_s += stot;
    }
    __syncthreads();
    if (t == 0) offs[N] = carry_s;
}

__global__ __launch_bounds__(256) void fill_elist(
    const int* __restrict__ ei, const int* __restrict__ offs,
    int* __restrict__ cnt2, int* __restrict__ elist,
    int* __restrict__ ssrc, int* __restrict__ sdst, int E)
{
    int e = blockIdx.x * 256 + threadIdx.x;
    if (e >= E) return;
    int d = ei[E + e];
    int p = offs[d] + atomicAdd(&cnt2[d], 1);
    elist[p] = e;
    ssrc[p] = ei[e];
    sdst[p] = d;
}

// ============ fused: softmax + gather-aggregate(Y) + relu + GEMV + sigmoid =====
// one wave per dst node; 4 dsts per 256-thread block; per-edge data in sorted order
__global__ __launch_bounds__(256) void gat_out(
    const __hip_bfloat16* __restrict__ Y,     // [N,4,512] bf16
    const int* __restrict__ ssrc, const int* __restrict__ offs,
    const float* __restrict__ logits,         // [E,4] sorted
    const float* __restrict__ bias2,
    const float* __restrict__ Wd2,            // [512,6]
    const float* __restrict__ bd2,
    float* __restrict__ out, int N)
{
    __shared__ float wds[512 * 6];   // 12 KB
    int t = threadIdx.x;
    for (int i = t; i < 512 * 6; i += 256) wds[i] = Wd2[i];
    __syncthreads();
    int w = t >> 6, lane = t & 63;
    int dst = blockIdx.x * 4 + w;
    if (dst >= N) return;
    int s = offs[dst], cntE = offs[dst + 1] - s;

    float den[4] = {0.f, 0.f, 0.f, 0.f};
    for (int i = 0; i < cntE; ++i) {
        #pragma unroll
        for (int h = 0; h < 4; ++h) den[h] += expf(logits[(s + i) * 4 + h]);
    }
    float acc[8] = {0.f, 0.f, 0.f, 0.f, 0.f, 0.f, 0.f, 0.f};
    for (int i = 0; i < cntE; ++i) {
        int p = s + i;
        int src = ssrc[p];
        #pragma unroll
        for (int h = 0; h < 4; ++h) {
            float al = expf(logits[p * 4 + h]) / (den[h] + 1e-16f);
            uint4 q = *(const uint4*)((const unsigned short*)Y
                        + ((size_t)src * 4 + h) * 512 + lane * 8);
            acc[0] += al * bfu((unsigned short)(q.x & 0xffff));
            acc[1] += al * bfu((unsigned short)(q.x >> 16));
            acc[2] += al * bfu((unsigned short)(q.y & 0xffff));
            acc[3] += al * bfu((unsigned short)(q.y >> 16));
            acc[4] += al * bfu((unsigned short)(q.z & 0xffff));
            acc[5] += al * bfu((unsigned short)(q.z >> 16));
            acc[6] += al * bfu((unsigned short)(q.w & 0xffff));
            acc[7] += al * bfu((unsigned short)(q.w >> 16));
        }
    }
    float p6[6] = {0.f, 0.f, 0.f, 0.f, 0.f, 0.f};
    #pragma unroll
    for (int j = 0; j < 8; ++j) {
        int c = lane * 8 + j;
        float u = fmaxf(acc[j] + bias2[c], 0.f);
        #pragma unroll
        for (int jj = 0; jj < 6; ++jj) p6[jj] += u * wds[c * 6 + jj];
    }
    #pragma unroll
    for (int off = 32; off; off >>= 1)
        #pragma unroll
        for (int jj = 0; jj < 6; ++jj) p6[jj] += __shfl_down(p6[jj], off);
    if (lane == 0) {
        #pragma unroll
        for (int jj = 0; jj < 6; ++jj)
            out[(size_t)dst * 6 + jj] = 1.f / (1.f + expf(-(p6[jj] + bd2[jj])));
    }
}

// ============ bias2 = b_d1 + conv_bias @ W_d1 ============
__global__ __launch_bounds__(256) void bias2_kernel(
    const float* __restrict__ bd1, const float* __restrict__ cb,
    const float* __restrict__ Wd1, float* __restrict__ bias2)
{
    int j = blockIdx.x * 256 + threadIdx.x;
    if (j >= 512) return;
    float acc = bd1[j];
    for (int k = 0; k < 2048; ++k) acc += cb[k] * Wd1[(size_t)k * 512 + j];
    bias2[j] = acc;
}

extern "C" void kernel_launch(void* const* d_in, const int* in_sizes, int n_in,
                              void* d_out, int out_size, void* d_ws, size_t ws_size,
                              hipStream_t stream)
{
    const float* x         = (const float*)d_in[0];
    const float* edge_attr = (const float*)d_in[1];
    const int*   ei        = (const int*)d_in[2];
    const float* W_node = (const float*)d_in[3],  *b_node = (const float*)d_in[4];
    const float* W_edge = (const float*)d_in[5],  *b_edge = (const float*)d_in[6];
    const float* W_l    = (const float*)d_in[7],  *b_l    = (const float*)d_in[8];
    const float* W_r    = (const float*)d_in[9],  *b_r    = (const float*)d_in[10];
    const float* W_le   = (const float*)d_in[11];
    const float* att    = (const float*)d_in[12];
    const float* conv_bias = (const float*)d_in[13];
    const float* W_d1   = (const float*)d_in[14], *b_d1 = (const float*)d_in[15];
    const float* W_d2   = (const float*)d_in[16], *b_d2 = (const float*)d_in[17];
    float* out = (float*)d_out;

    const int N = in_sizes[0] / 7;   // 25000
    const int E = in_sizes[1] / 2;   // 50000
    const int MP = (N + 127) & ~127; // padded rows (unguarded async A-reads)
    const int EP = (E + 127) & ~127;

    // ---- workspace layout (~268 MB) ----
    char* ws = (char*)d_ws;
    const size_t szR0 = (size_t)EP * 512 * 2;     // h bf16[MP,512] then ea bf16[EP,512]
    const size_t szX  = (size_t)MP * 2048 * 2;
    const size_t szW  = (size_t)2048 * 512 * 2;
    const size_t szlg = (size_t)E * 4 * 4;
    const size_t szI  = (((size_t)(N + 1) * 4) + 15) & ~(size_t)15;
    const size_t o_XL = szR0;
    const size_t o_XR = o_XL + szX;
    const size_t o_W  = o_XR + szX;                // WlT,WrT contiguous (grid.z=2)
    const size_t o_lg = o_W + 4 * szW;
    const size_t o_b2 = o_lg + szlg;
    const size_t o_bc = o_b2 + 2048;
    const size_t o_cnt = o_bc + 4096 * 4;
    const size_t o_cnt2 = o_cnt + szI;
    const size_t o_off = o_cnt2 + szI;
    const size_t o_el = o_off + szI;
    const size_t o_ss = o_el + (size_t)E * 4;
    const size_t o_sd = o_ss + (size_t)E * 4;
    const size_t need = o_sd + (size_t)E * 4;
    if (ws_size < need) return;   // clean diagnostic failure if ws too small

    __hip_bfloat16* h   = (__hip_bfloat16*)ws;
    __hip_bfloat16* ea  = (__hip_bfloat16*)ws;
    __hip_bfloat16* XL  = (__hip_bfloat16*)(ws + o_XL);
    __hip_bfloat16* XR  = (__hip_bfloat16*)(ws + o_XR);
    __hip_bfloat16* Y   = XR;                       // overlays XR after logits
    __hip_bfloat16* WlT = (__hip_bfloat16*)(ws + o_W);
    __hip_bfloat16* WrT = WlT + szW / 2;
    __hip_bfloat16* WleT= WrT + szW / 2;
    __hip_bfloat16* Wd1T= WleT + szW / 2;
    float* logits = (float*)(ws + o_lg);
    float* bias2  = (float*)(ws + o_b2);
    float* bcat   = (float*)(ws + o_bc);
    int* cnt   = (int*)(ws + o_cnt);
    int* cnt2  = (int*)(ws + o_cnt2);
    int* offs  = (int*)(ws + o_off);
    int* elist = (int*)(ws + o_el);
    int* ssrc  = (int*)(ws + o_ss);
    int* sdst  = (int*)(ws + o_sd);

    hipMemsetAsync(logits, 0, szlg, stream);
    hipMemsetAsync(cnt, 0, szI, stream);
    hipMemsetAsync(cnt2, 0, szI, stream);
    hipMemcpyAsync(bcat, b_l, 2048 * 4, hipMemcpyDeviceToDevice, stream);
    hipMemcpyAsync(bcat + 2048, b_r, 2048 * 4, hipMemcpyDeviceToDevice, stream);

    // weight prep: [K,N] fp32 -> [N,K] bf16
    dim3 gT(512 / 32, 2048 / 32);
    transpose_bf16<<<gT, 256, 0, stream>>>(W_l,  WlT, 512, 2048);
    transpose_bf16<<<gT, 256, 0, stream>>>(W_r,  WrT, 512, 2048);
    transpose_bf16<<<gT, 256, 0, stream>>>(W_le, WleT, 512, 2048);
    dim3 gT2(2048 / 32, 512 / 32);
    transpose_bf16<<<gT2, 256, 0, stream>>>(W_d1, Wd1T, 2048, 512);
    bias2_kernel<<<2, 256, 0, stream>>>(b_d1, conv_bias, W_d1, bias2);

    // counting sort of edges by dst; emits sorted src/dst arrays
    count_dst<<<(E + 255) / 256, 256, 0, stream>>>(ei, cnt, E);
    scan_kernel<<<1, 1024, 0, stream>>>(cnt, offs, N);
    fill_elist<<<(E + 255) / 256, 256, 0, stream>>>(ei, offs, cnt2, elist, ssrc, sdst, E);

    encode_nodes<<<(N * 512 + 255) / 256, 256, 0, stream>>>(x, W_node, b_node, h, N);

    const int MB = MP / 128;
    // XL and XR in ONE launch: z selects {WlT,b_l,XL} vs {WrT,b_r,XR}
    dim3 gNode(2048 / 128, MB, 2);
    mfma_gemm<__hip_bfloat16, true><<<gNode, 256, 0, stream>>>(
        h, 512, 0, WlT, 512, (long)2048 * 512, bcat, 2048,
        XL, 2048, (long)MP * 2048, N, 512);

    // h dead -> region0 becomes ea (sorted edge order)
    encode_edges_sorted<<<(E * 512 + 255) / 256, 256, 0, stream>>>(
        edge_attr, elist, W_edge, b_edge, ea, E);

    dim3 gE(16, EP / 128);                            // x = col tile (fast)
    edge_mfma_logits<<<gE, 256, 0, stream>>>(ea, WleT, XL, XR, ssrc, sdst, att, logits, E);

    // Y[n, hh*512+c] = XL[n, hh*512:] @ W_d1[hh*512:, :]  (block-diag, grid.z=4)
    dim3 gY(512 / 128, MB, 4);
    mfma_gemm<__hip_bfloat16, false><<<gY, 256, 0, stream>>>(
        XL, 2048, 512, Wd1T, 2048, 512, nullptr, 0, Y, 2048, 512, N, 512);

    gat_out<<<(N + 3) / 4, 256, 0, stream>>>(Y, ssrc, offs, logits,
                                             bias2, W_d2, b_d2, out, N);
}

// Round 10
// 729.474 us; speedup vs baseline: 1.0820x; 1.0708x over previous
//
#include <hip/hip_runtime.h>
#include <hip/hip_bf16.h>

typedef __attribute__((ext_vector_type(8))) short short8;
typedef __attribute__((ext_vector_type(4))) float f32x4;
typedef unsigned int uint32;

// async global->LDS, 16B per lane; LDS dest = uniform base + lane*16
#define GLD16(g, l) __builtin_amdgcn_global_load_lds( \
    (const __attribute__((address_space(1))) unsigned int*)(g), \
    (__attribute__((address_space(3))) unsigned int*)(l), 16, 0, 0)

__device__ __forceinline__ float bfu(unsigned short u) {
    union { uint32 v; float f; } x; x.v = ((uint32)u) << 16; return x.f;
}
__device__ __forceinline__ void storev(float* p, float v) { *p = v; }
__device__ __forceinline__ void storev(__hip_bfloat16* p, float v) { *p = __float2bfloat16(v); }

// ============ transpose fp32 [K,N] -> bf16 [N,K] ============
__global__ __launch_bounds__(256) void transpose_bf16(
    const float* __restrict__ W, __hip_bfloat16* __restrict__ WT, int K, int N)
{
    __shared__ float tile[32][33];
    int k0 = blockIdx.x * 32, n0 = blockIdx.y * 32;
    int tx = threadIdx.x & 31, ty = threadIdx.x >> 5;   // 32 x 8
    #pragma unroll
    for (int i = 0; i < 32; i += 8)
        tile[ty + i][tx] = W[(size_t)(k0 + ty + i) * N + n0 + tx];
    __syncthreads();
    #pragma unroll
    for (int i = 0; i < 32; i += 8)
        WT[(size_t)(n0 + ty + i) * K + k0 + tx] = __float2bfloat16(tile[tx][ty + i]);
}

// ============ encoders ============
__global__ __launch_bounds__(256) void encode_nodes(
    const float* __restrict__ x, const float* __restrict__ Wn,
    const float* __restrict__ bn, __hip_bfloat16* __restrict__ h, int Nn)
{
    int idx = blockIdx.x * 256 + threadIdx.x;
    if (idx >= Nn * 512) return;
    int n = idx >> 9, c = idx & 511;
    float acc = bn[c];
    #pragma unroll
    for (int f = 0; f < 7; ++f) acc += x[n * 7 + f] * Wn[f * 512 + c];
    h[idx] = __float2bfloat16(fmaxf(acc, 0.f));
}

// edge encoder writing rows in dst-sorted order: ea[p] = relu(f(edge_attr[elist[p]]))
__global__ __launch_bounds__(256) void encode_edges_sorted(
    const float* __restrict__ eat, const int* __restrict__ elist,
    const float* __restrict__ We, const float* __restrict__ be,
    __hip_bfloat16* __restrict__ ea, int E)
{
    int idx = blockIdx.x * 256 + threadIdx.x;
    if (idx >= E * 512) return;
    int p = idx >> 9, c = idx & 511;
    int e = elist[p];
    float v = fmaf(eat[e * 2], We[c], fmaf(eat[e * 2 + 1], We[512 + c], be[c]));
    ea[idx] = __float2bfloat16(fmaxf(v, 0.f));
}

// ============ bf16 MFMA GEMM, BK=64 (32 MFMAs per barrier pair) ============
// LDS tile [128 rows][64 k-elems] (128 B/row), chunk-swizzle p = l ^ (row&7)
// applied on the GLOBAL source; linear LDS dest (global_load_lds constraint).
template <typename OutT, bool HAS_BIAS>
__global__ __launch_bounds__(256) void mfma_gemm(
    const __hip_bfloat16* __restrict__ A, int lda, long az,
    const __hip_bfloat16* __restrict__ BT, int ldb, long bz,
    const float* __restrict__ bias, long biasz,
    OutT* __restrict__ C, int ldc, long cz, int M, int K)
{
    __shared__ uint4 As4[1024];   // 16 KB
    __shared__ uint4 Bs4[1024];
    A  += (long)blockIdx.z * az;
    BT += (long)blockIdx.z * bz;
    C  += (long)blockIdx.z * cz;
    if (HAS_BIAS) bias += (long)blockIdx.z * biasz;
    const int t = threadIdx.x, lane = t & 63, w = t >> 6;
    const int wr = (w >> 1) * 64, wc = (w & 1) * 64;
    const int col0 = blockIdx.x * 128, row0 = blockIdx.y * 128;  // x = col tile (fast)
    const int lr = lane & 15, lg = lane >> 4;
    const int srow8 = lane >> 3;             // 0..7 row within 8-row staging stripe
    const int sch   = (lane & 7) ^ srow8;    // logical 16B chunk (pre-swizzled source)
    const int rx = lr & 7;                   // read-side swizzle key

    const __hip_bfloat16* ApL = A + (size_t)(row0 + srow8) * lda + sch * 8;
    const __hip_bfloat16* BpL = BT + (size_t)(col0 + srow8) * ldb + sch * 8;

    f32x4 acc[4][4];
    #pragma unroll
    for (int m = 0; m < 4; ++m)
        #pragma unroll
        for (int n = 0; n < 4; ++n) acc[m][n] = 0.f;

    for (int k0 = 0; k0 < K; k0 += 64) {
        #pragma unroll
        for (int j = 0; j < 4; ++j) {
            int rb = (w + 4 * j) * 8;
            GLD16(ApL + (size_t)rb * lda + k0, As4 + (w + 4 * j) * 64);
            GLD16(BpL + (size_t)rb * ldb + k0, Bs4 + (w + 4 * j) * 64);
        }
        __syncthreads();
        #pragma unroll
        for (int kk = 0; kk < 2; ++kk) {
            short8 af[4], bfrag[4];
            #pragma unroll
            for (int m = 0; m < 4; ++m) {
                int row = wr + m * 16 + lr;
                af[m] = *(const short8*)((const char*)As4 + row * 128 + (((kk * 4 + lg) ^ rx) << 4));
            }
            #pragma unroll
            for (int n = 0; n < 4; ++n) {
                int row = wc + n * 16 + lr;
                bfrag[n] = *(const short8*)((const char*)Bs4 + row * 128 + (((kk * 4 + lg) ^ rx) << 4));
            }
            #pragma unroll
            for (int m = 0; m < 4; ++m)
                #pragma unroll
                for (int n = 0; n < 4; ++n)
                    acc[m][n] = __builtin_amdgcn_mfma_f32_16x16x32_bf16(af[m], bfrag[n], acc[m][n], 0, 0, 0);
        }
        __syncthreads();
    }

    #pragma unroll
    for (int m = 0; m < 4; ++m) {
        #pragma unroll
        for (int r = 0; r < 4; ++r) {
            int gr = row0 + wr + m * 16 + lg * 4 + r;
            if (gr >= M) continue;
            #pragma unroll
            for (int n = 0; n < 4; ++n) {
                int gc = col0 + wc + n * 16 + lr;
                float v = acc[m][n][r];
                if (HAS_BIAS) v += bias[gc];
                storev(&C[(size_t)gr * ldc + gc], v);
            }
        }
    }
}

// ============ edge GEMM (BK=64) + fused logits, sorted-edge space ============
__global__ __launch_bounds__(256) void edge_mfma_logits(
    const __hip_bfloat16* __restrict__ ea,    // [EP,512] (sorted rows)
    const __hip_bfloat16* __restrict__ WleT,  // [2048,512]
    const __hip_bfloat16* __restrict__ XL,
    const __hip_bfloat16* __restrict__ XR,
    const int* __restrict__ ssrc,             // [E] src per sorted pos
    const int* __restrict__ sdst,             // [E] dst per sorted pos
    const float* __restrict__ att,
    float* __restrict__ logits,               // [E,4] pre-zeroed, atomic partial
    int E)
{
    __shared__ uint4 As4[1024];
    __shared__ uint4 Bs4[1024];
    __shared__ int srcs[128], dsts[128];
    const int t = threadIdx.x, lane = t & 63, w = t >> 6;
    const int wr = (w >> 1) * 64, wc = (w & 1) * 64;
    const int col0 = blockIdx.x * 128, row0 = blockIdx.y * 128;  // x = col tile (fast)
    const int lr = lane & 15, lg = lane >> 4;
    const int srow8 = lane >> 3;
    const int sch   = (lane & 7) ^ srow8;
    const int rx = lr & 7;

    if (t < 128) {
        int ge = row0 + t;
        bool ok = ge < E;
        srcs[t] = ok ? ssrc[ge] : 0;
        dsts[t] = ok ? sdst[ge] : 0;
    }
    const __hip_bfloat16* ApL = ea + (size_t)(row0 + srow8) * 512 + sch * 8;
    const __hip_bfloat16* BpL = WleT + (size_t)(col0 + srow8) * 512 + sch * 8;
    __syncthreads();

    f32x4 acc[4][4];
    #pragma unroll
    for (int m = 0; m < 4; ++m)
        #pragma unroll
        for (int n = 0; n < 4; ++n) acc[m][n] = 0.f;

    for (int k0 = 0; k0 < 512; k0 += 64) {
        #pragma unroll
        for (int j = 0; j < 4; ++j) {
            int rb = (w + 4 * j) * 8;
            GLD16(ApL + (size_t)rb * 512 + k0, As4 + (w + 4 * j) * 64);
            GLD16(BpL + (size_t)rb * 512 + k0, Bs4 + (w + 4 * j) * 64);
        }
        __syncthreads();
        #pragma unroll
        for (int kk = 0; kk < 2; ++kk) {
            short8 af[4], bfrag[4];
            #pragma unroll
            for (int m = 0; m < 4; ++m) {
                int row = wr + m * 16 + lr;
                af[m] = *(const short8*)((const char*)As4 + row * 128 + (((kk * 4 + lg) ^ rx) << 4));
            }
            #pragma unroll
            for (int n = 0; n < 4; ++n) {
                int row = wc + n * 16 + lr;
                bfrag[n] = *(const short8*)((const char*)Bs4 + row * 128 + (((kk * 4 + lg) ^ rx) << 4));
            }
            #pragma unroll
            for (int m = 0; m < 4; ++m)
                #pragma unroll
                for (int n = 0; n < 4; ++n)
                    acc[m][n] = __builtin_amdgcn_mfma_f32_16x16x32_bf16(af[m], bfrag[n], acc[m][n], 0, 0, 0);
        }
        __syncthreads();
    }

    // ---- logits epilogue: XL/XR 32-col strips; 2 strips per drain, balanced ----
    const int hh = col0 >> 9;
    float attv[4];
    #pragma unroll
    for (int n = 0; n < 4; ++n)
        attv[n] = att[hh * 512 + ((col0 + wc + n * 16 + lr) & 511)];
    float part[4][4];
    #pragma unroll
    for (int m = 0; m < 4; ++m)
        #pragma unroll
        for (int r = 0; r < 4; ++r) part[m][r] = 0.f;

    const int prt = (lane & 3) * 8;           // 8-elem sub-chunk within 32-col strip
    const int r0e = w * 16 + (lane >> 2);     // strip staging row
    const int s0 = srcs[r0e], s1 = srcs[r0e + 64];
    const int d0 = dsts[r0e], d1 = dsts[r0e + 64];

    #pragma unroll
    for (int pair = 0; pair < 2; ++pair) {
        // stage strips {pair, pair+2} — one strip from each wave-half's range
        #pragma unroll
        for (int sp = 0; sp < 2; ++sp) {
            int ch = pair + sp * 2;
            int cc = col0 + ch * 32;
            GLD16(XL + (size_t)s0 * 2048 + cc + prt, As4 + sp * 512 + w * 64);
            GLD16(XL + (size_t)s1 * 2048 + cc + prt, As4 + sp * 512 + (w + 4) * 64);
            GLD16(XR + (size_t)d0 * 2048 + cc + prt, Bs4 + sp * 512 + w * 64);
            GLD16(XR + (size_t)d1 * 2048 + cc + prt, Bs4 + sp * 512 + (w + 4) * 64);
        }
        __syncthreads();   // drain staged strips
        #pragma unroll
        for (int sp = 0; sp < 2; ++sp) {
            int ch = pair + sp * 2;
            const char* AsB = (const char*)(As4 + sp * 512);
            const char* BsB = (const char*)(Bs4 + sp * 512);
            #pragma unroll
            for (int n = 0; n < 4; ++n) {
                if (((wc + n * 16) >> 5) != ch) continue;
                int colin = ((n & 1) << 4) + lr;
                #pragma unroll
                for (int m = 0; m < 4; ++m) {
                    #pragma unroll
                    for (int r = 0; r < 4; ++r) {
                        int row = wr + m * 16 + lg * 4 + r;
                        float xl = bfu(*(const unsigned short*)(AsB + row * 64 + colin * 2));
                        float xr = bfu(*(const unsigned short*)(BsB + row * 64 + colin * 2));
                        float mv = acc[m][n][r] + xl + xr;
                        part[m][r] += attv[n] * ((mv > 0.f) ? mv : 0.2f * mv);
                    }
                }
            }
        }
        __syncthreads();   // strip reads done; buffers reusable
    }
    #pragma unroll
    for (int m = 0; m < 4; ++m) {
        #pragma unroll
        for (int r = 0; r < 4; ++r) {
            float p = part[m][r];
            p += __shfl_xor(p, 1); p += __shfl_xor(p, 2);
            p += __shfl_xor(p, 4); p += __shfl_xor(p, 8);
            int ge = row0 + wr + m * 16 + lg * 4 + r;
            if (lr == 0 && ge < E) atomicAdd(&logits[ge * 4 + hh], p);
        }
    }
}

// ============ counting sort of edges by dst ============
__global__ __launch_bounds__(256) void count_dst(
    const int* __restrict__ ei, int* __restrict__ cnt, int E)
{
    int e = blockIdx.x * 256 + threadIdx.x;
    if (e < E) atomicAdd(&cnt[ei[E + e]], 1);
}

// single-block hierarchical exclusive scan: offs[0..N], offs[N] = total
__global__ __launch_bounds__(1024) void scan_kernel(
    const int* __restrict__ cnt, int* __restrict__ offs, int N)
{
    __shared__ int wsum[16];
    __shared__ int stot;
    __shared__ int carry_s;
    int t = threadIdx.x, lane = t & 63, w = t >> 6;
    if (t == 0) carry_s = 0;
    __syncthreads();
    for (int base = 0; base < N; base += 1024) {
        int v = (base + t < N) ? cnt[base + t] : 0;
        int x = v;
        #pragma unroll
        for (int off = 1; off < 64; off <<= 1) {
            int y = __shfl_up(x, off);
            if (lane >= off) x += y;
        }
        if (lane == 63) wsum[w] = x;
        __syncthreads();                       // (A) wsum ready
        if (w == 0 && lane < 16) {
            int v0 = wsum[lane];
            int s = v0;
            #pragma unroll
            for (int off = 1; off < 16; off <<= 1) {
                int y = __shfl_up(s, off);
                if (lane >= off) s += y;
            }
            wsum[lane] = s - v0;               // exclusive prefix of wave sums
            if (lane == 15) stot = s;          // chunk total
        }
        __syncthreads();                       // (B) wsum/stot ready
        if (base + t < N) offs[base + t] = carry_s + wsum[w] + x - v;
        __syncthreads();                       // (C) carry_s reads done
        if (t == 0) carry_s += stot;
    }
    __syncthreads();
    if (t == 0) offs[N] = carry_s;
}

__global__ __launch_bounds__(256) void fill_elist(
    const int* __restrict__ ei, const int* __restrict__ offs,
    int* __restrict__ cnt2, int* __restrict__ elist,
    int* __restrict__ ssrc, int* __restrict__ sdst, int E)
{
    int e = blockIdx.x * 256 + threadIdx.x;
    if (e >= E) return;
    int d = ei[E + e];
    int p = offs[d] + atomicAdd(&cnt2[d], 1);
    elist[p] = e;
    ssrc[p] = ei[e];
    sdst[p] = d;
}

// ============ fused: softmax + gather-aggregate(Y) + relu + GEMV + sigmoid =====
// one wave per dst node; 4 dsts per 256-thread block; per-edge data in sorted order
__global__ __launch_bounds__(256) void gat_out(
    const __hip_bfloat16* __restrict__ Y,     // [N,4,512] bf16
    const int* __restrict__ ssrc, const int* __restrict__ offs,
    const float* __restrict__ logits,         // [E,4] sorted
    const float* __restrict__ bias2,
    const float* __restrict__ Wd2,            // [512,6]
    const float* __restrict__ bd2,
    float* __restrict__ out, int N)
{
    __shared__ float wds[512 * 6];   // 12 KB
    int t = threadIdx.x;
    for (int i = t; i < 512 * 6; i += 256) wds[i] = Wd2[i];
    __syncthreads();
    int w = t >> 6, lane = t & 63;
    int dst = blockIdx.x * 4 + w;
    if (dst >= N) return;
    int s = offs[dst], cntE = offs[dst + 1] - s;

    float den[4] = {0.f, 0.f, 0.f, 0.f};
    for (int i = 0; i < cntE; ++i) {
        #pragma unroll
        for (int h = 0; h < 4; ++h) den[h] += expf(logits[(s + i) * 4 + h]);
    }
    float acc[8] = {0.f, 0.f, 0.f, 0.f, 0.f, 0.f, 0.f, 0.f};
    for (int i = 0; i < cntE; ++i) {
        int p = s + i;
        int src = ssrc[p];
        #pragma unroll
        for (int h = 0; h < 4; ++h) {
            float al = expf(logits[p * 4 + h]) / (den[h] + 1e-16f);
            uint4 q = *(const uint4*)((const unsigned short*)Y
                        + ((size_t)src * 4 + h) * 512 + lane * 8);
            acc[0] += al * bfu((unsigned short)(q.x & 0xffff));
            acc[1] += al * bfu((unsigned short)(q.x >> 16));
            acc[2] += al * bfu((unsigned short)(q.y & 0xffff));
            acc[3] += al * bfu((unsigned short)(q.y >> 16));
            acc[4] += al * bfu((unsigned short)(q.z & 0xffff));
            acc[5] += al * bfu((unsigned short)(q.z >> 16));
            acc[6] += al * bfu((unsigned short)(q.w & 0xffff));
            acc[7] += al * bfu((unsigned short)(q.w >> 16));
        }
    }
    float p6[6] = {0.f, 0.f, 0.f, 0.f, 0.f, 0.f};
    #pragma unroll
    for (int j = 0; j < 8; ++j) {
        int c = lane * 8 + j;
        float u = fmaxf(acc[j] + bias2[c], 0.f);
        #pragma unroll
        for (int jj = 0; jj < 6; ++jj) p6[jj] += u * wds[c * 6 + jj];
    }
    #pragma unroll
    for (int off = 32; off; off >>= 1)
        #pragma unroll
        for (int jj = 0; jj < 6; ++jj) p6[jj] += __shfl_down(p6[jj], off);
    if (lane == 0) {
        #pragma unroll
        for (int jj = 0; jj < 6; ++jj)
            out[(size_t)dst * 6 + jj] = 1.f / (1.f + expf(-(p6[jj] + bd2[jj])));
    }
}

// ============ bias2 = b_d1 + conv_bias @ W_d1 ============
__global__ __launch_bounds__(256) void bias2_kernel(
    const float* __restrict__ bd1, const float* __restrict__ cb,
    const float* __restrict__ Wd1, float* __restrict__ bias2)
{
    int j = blockIdx.x * 256 + threadIdx.x;
    if (j >= 512) return;
    float acc = bd1[j];
    for (int k = 0; k < 2048; ++k) acc += cb[k] * Wd1[(size_t)k * 512 + j];
    bias2[j] = acc;
}

extern "C" void kernel_launch(void* const* d_in, const int* in_sizes, int n_in,
                              void* d_out, int out_size, void* d_ws, size_t ws_size,
                              hipStream_t stream)
{
    const float* x         = (const float*)d_in[0];
    const float* edge_attr = (const float*)d_in[1];
    const int*   ei        = (const int*)d_in[2];
    const float* W_node = (const float*)d_in[3],  *b_node = (const float*)d_in[4];
    const float* W_edge = (const float*)d_in[5],  *b_edge = (const float*)d_in[6];
    const float* W_l    = (const float*)d_in[7],  *b_l    = (const float*)d_in[8];
    const float* W_r    = (const float*)d_in[9],  *b_r    = (const float*)d_in[10];
    const float* W_le   = (const float*)d_in[11];
    const float* att    = (const float*)d_in[12];
    const float* conv_bias = (const float*)d_in[13];
    const float* W_d1   = (const float*)d_in[14], *b_d1 = (const float*)d_in[15];
    const float* W_d2   = (const float*)d_in[16], *b_d2 = (const float*)d_in[17];
    float* out = (float*)d_out;

    const int N = in_sizes[0] / 7;   // 25000
    const int E = in_sizes[1] / 2;   // 50000
    const int MP = (N + 127) & ~127; // padded rows (unguarded async A-reads)
    const int EP = (E + 127) & ~127;

    // ---- workspace layout (~268 MB) ----
    char* ws = (char*)d_ws;
    const size_t szR0 = (size_t)EP * 512 * 2;     // h bf16[MP,512] then ea bf16[EP,512]
    const size_t szX  = (size_t)MP * 2048 * 2;
    const size_t szW  = (size_t)2048 * 512 * 2;
    const size_t szlg = (size_t)E * 4 * 4;
    const size_t szI  = (((size_t)(N + 1) * 4) + 15) & ~(size_t)15;
    const size_t o_XL = szR0;
    const size_t o_XR = o_XL + szX;
    const size_t o_W  = o_XR + szX;                // WlT,WrT contiguous (grid.z=2)
    const size_t o_lg = o_W + 4 * szW;
    const size_t o_b2 = o_lg + szlg;
    const size_t o_bc = o_b2 + 2048;
    const size_t o_cnt = o_bc + 4096 * 4;
    const size_t o_cnt2 = o_cnt + szI;
    const size_t o_off = o_cnt2 + szI;
    const size_t o_el = o_off + szI;
    const size_t o_ss = o_el + (size_t)E * 4;
    const size_t o_sd = o_ss + (size_t)E * 4;
    const size_t need = o_sd + (size_t)E * 4;
    if (ws_size < need) return;   // clean diagnostic failure if ws too small

    __hip_bfloat16* h   = (__hip_bfloat16*)ws;
    __hip_bfloat16* ea  = (__hip_bfloat16*)ws;
    __hip_bfloat16* XL  = (__hip_bfloat16*)(ws + o_XL);
    __hip_bfloat16* XR  = (__hip_bfloat16*)(ws + o_XR);
    __hip_bfloat16* Y   = XR;                       // overlays XR after logits
    __hip_bfloat16* WlT = (__hip_bfloat16*)(ws + o_W);
    __hip_bfloat16* WrT = WlT + szW / 2;
    __hip_bfloat16* WleT= WrT + szW / 2;
    __hip_bfloat16* Wd1T= WleT + szW / 2;
    float* logits = (float*)(ws + o_lg);
    float* bias2  = (float*)(ws + o_b2);
    float* bcat   = (float*)(ws + o_bc);
    int* cnt   = (int*)(ws + o_cnt);
    int* cnt2  = (int*)(ws + o_cnt2);
    int* offs  = (int*)(ws + o_off);
    int* elist = (int*)(ws + o_el);
    int* ssrc  = (int*)(ws + o_ss);
    int* sdst  = (int*)(ws + o_sd);

    hipMemsetAsync(logits, 0, szlg, stream);
    hipMemsetAsync(cnt, 0, szI, stream);
    hipMemsetAsync(cnt2, 0, szI, stream);
    hipMemcpyAsync(bcat, b_l, 2048 * 4, hipMemcpyDeviceToDevice, stream);
    hipMemcpyAsync(bcat + 2048, b_r, 2048 * 4, hipMemcpyDeviceToDevice, stream);

    // weight prep: [K,N] fp32 -> [N,K] bf16
    dim3 gT(512 / 32, 2048 / 32);
    transpose_bf16<<<gT, 256, 0, stream>>>(W_l,  WlT, 512, 2048);
    transpose_bf16<<<gT, 256, 0, stream>>>(W_r,  WrT, 512, 2048);
    transpose_bf16<<<gT, 256, 0, stream>>>(W_le, WleT, 512, 2048);
    dim3 gT2(2048 / 32, 512 / 32);
    transpose_bf16<<<gT2, 256, 0, stream>>>(W_d1, Wd1T, 2048, 512);
    bias2_kernel<<<2, 256, 0, stream>>>(b_d1, conv_bias, W_d1, bias2);

    // counting sort of edges by dst; emits sorted src/dst arrays
    count_dst<<<(E + 255) / 256, 256, 0, stream>>>(ei, cnt, E);
    scan_kernel<<<1, 1024, 0, stream>>>(cnt, offs, N);
    fill_elist<<<(E + 255) / 256, 256, 0, stream>>>(ei, offs, cnt2, elist, ssrc, sdst, E);

    encode_nodes<<<(N * 512 + 255) / 256, 256, 0, stream>>>(x, W_node, b_node, h, N);

    const int MB = MP / 128;
    // XL and XR in ONE launch: z selects {WlT,b_l,XL} vs {WrT,b_r,XR}
    dim3 gNode(2048 / 128, MB, 2);
    mfma_gemm<__hip_bfloat16, true><<<gNode, 256, 0, stream>>>(
        h, 512, 0, WlT, 512, (long)2048 * 512, bcat, 2048,
        XL, 2048, (long)MP * 2048, N, 512);

    // h dead -> region0 becomes ea (sorted edge order)
    encode_edges_sorted<<<(E * 512 + 255) / 256, 256, 0, stream>>>(
        edge_attr, elist, W_edge, b_edge, ea, E);

    dim3 gE(16, EP / 128);                            // x = col tile (fast)
    edge_mfma_logits<<<gE, 256, 0, stream>>>(ea, WleT, XL, XR, ssrc, sdst, att, logits, E);

    // Y[n, hh*512+c] = XL[n, hh*512:] @ W_d1[hh*512:, :]  (block-diag, grid.z=4)
    dim3 gY(512 / 128, MB, 4);
    mfma_gemm<__hip_bfloat16, false><<<gY, 256, 0, stream>>>(
        XL, 2048, 512, Wd1T, 2048, 512, nullptr, 0, Y, 2048, 512, N, 512);

    gat_out<<<(N + 3) / 4, 256, 0, stream>>>(Y, ssrc, offs, logits,
                                             bias2, W_d2, b_d2, out, N);
}

// Round 12
// 709.436 us; speedup vs baseline: 1.1125x; 1.0282x over previous
//
#include <hip/hip_runtime.h>
#include <hip/hip_bf16.h>

typedef __attribute__((ext_vector_type(8))) short short8;
typedef __attribute__((ext_vector_type(4))) float f32x4;
typedef unsigned int uint32;

#define GLD16(g, l) __builtin_amdgcn_global_load_lds( \
    (const __attribute__((address_space(1))) unsigned int*)(g), \
    (__attribute__((address_space(3))) unsigned int*)(l), 16, 0, 0)

__device__ __forceinline__ float bfu(unsigned short u) {
    union { uint32 v; float f; } x; x.v = ((uint32)u) << 16; return x.f;
}
__device__ __forceinline__ void storev(float* p, float v) { *p = v; }
__device__ __forceinline__ void storev(__hip_bfloat16* p, float v) { *p = __float2bfloat16(v); }

// ============ transpose fp32 [K,N] -> bf16 [N,K] ============
__global__ __launch_bounds__(256) void transpose_bf16(
    const float* __restrict__ W, __hip_bfloat16* __restrict__ WT, int K, int N)
{
    __shared__ float tile[32][33];
    int k0 = blockIdx.x * 32, n0 = blockIdx.y * 32;
    int tx = threadIdx.x & 31, ty = threadIdx.x >> 5;   // 32 x 8
    #pragma unroll
    for (int i = 0; i < 32; i += 8)
        tile[ty + i][tx] = W[(size_t)(k0 + ty + i) * N + n0 + tx];
    __syncthreads();
    #pragma unroll
    for (int i = 0; i < 32; i += 8)
        WT[(size_t)(n0 + ty + i) * K + k0 + tx] = __float2bfloat16(tile[tx][ty + i]);
}

__global__ __launch_bounds__(256) void cast_bf16(
    const float* __restrict__ W, __hip_bfloat16* __restrict__ O, int total)
{
    int idx = blockIdx.x * 256 + threadIdx.x;
    if (idx < total) O[idx] = __float2bfloat16(W[idx]);
}

// ============ encoders ============
__global__ __launch_bounds__(256) void encode_nodes(
    const float* __restrict__ x, const float* __restrict__ Wn,
    const float* __restrict__ bn, __hip_bfloat16* __restrict__ h, int Nn)
{
    int idx = blockIdx.x * 256 + threadIdx.x;
    if (idx >= Nn * 512) return;
    int n = idx >> 9, c = idx & 511;
    float acc = bn[c];
    #pragma unroll
    for (int f = 0; f < 7; ++f) acc += x[n * 7 + f] * Wn[f * 512 + c];
    h[idx] = __float2bfloat16(fmaxf(acc, 0.f));
}

__global__ __launch_bounds__(256) void encode_edges_sorted(
    const float* __restrict__ eat, const int* __restrict__ elist,
    const float* __restrict__ We, const float* __restrict__ be,
    __hip_bfloat16* __restrict__ ea, int E)
{
    int idx = blockIdx.x * 256 + threadIdx.x;
    if (idx >= E * 512) return;
    int p = idx >> 9, c = idx & 511;
    int e = elist[p];
    float v = fmaf(eat[e * 2], We[c], fmaf(eat[e * 2 + 1], We[512 + c], be[c]));
    ea[idx] = __float2bfloat16(fmaxf(v, 0.f));
}

// ============ bf16 MFMA GEMM, BK=64 ============
template <typename OutT, bool HAS_BIAS>
__global__ __launch_bounds__(256) void mfma_gemm(
    const __hip_bfloat16* __restrict__ A, int lda, long az,
    const __hip_bfloat16* __restrict__ BT, int ldb, long bz,
    const float* __restrict__ bias, long biasz,
    OutT* __restrict__ C, int ldc, long cz, int M, int K)
{
    __shared__ uint4 As4[1024];   // 16 KB
    __shared__ uint4 Bs4[1024];
    A  += (long)blockIdx.z * az;
    BT += (long)blockIdx.z * bz;
    C  += (long)blockIdx.z * cz;
    if (HAS_BIAS) bias += (long)blockIdx.z * biasz;
    const int t = threadIdx.x, lane = t & 63, w = t >> 6;
    const int wr = (w >> 1) * 64, wc = (w & 1) * 64;
    const int col0 = blockIdx.x * 128, row0 = blockIdx.y * 128;  // x = col tile (fast)
    const int lr = lane & 15, lg = lane >> 4;
    const int srow8 = lane >> 3;
    const int sch   = (lane & 7) ^ srow8;
    const int rx = lr & 7;

    const __hip_bfloat16* ApL = A + (size_t)(row0 + srow8) * lda + sch * 8;
    const __hip_bfloat16* BpL = BT + (size_t)(col0 + srow8) * ldb + sch * 8;

    f32x4 acc[4][4];
    #pragma unroll
    for (int m = 0; m < 4; ++m)
        #pragma unroll
        for (int n = 0; n < 4; ++n) acc[m][n] = 0.f;

    for (int k0 = 0; k0 < K; k0 += 64) {
        #pragma unroll
        for (int j = 0; j < 4; ++j) {
            int rb = (w + 4 * j) * 8;
            GLD16(ApL + (size_t)rb * lda + k0, As4 + (w + 4 * j) * 64);
            GLD16(BpL + (size_t)rb * ldb + k0, Bs4 + (w + 4 * j) * 64);
        }
        __syncthreads();
        #pragma unroll
        for (int kk = 0; kk < 2; ++kk) {
            short8 af[4], bfrag[4];
            #pragma unroll
            for (int m = 0; m < 4; ++m) {
                int row = wr + m * 16 + lr;
                af[m] = *(const short8*)((const char*)As4 + row * 128 + (((kk * 4 + lg) ^ rx) << 4));
            }
            #pragma unroll
            for (int n = 0; n < 4; ++n) {
                int row = wc + n * 16 + lr;
                bfrag[n] = *(const short8*)((const char*)Bs4 + row * 128 + (((kk * 4 + lg) ^ rx) << 4));
            }
            #pragma unroll
            for (int m = 0; m < 4; ++m)
                #pragma unroll
                for (int n = 0; n < 4; ++n)
                    acc[m][n] = __builtin_amdgcn_mfma_f32_16x16x32_bf16(af[m], bfrag[n], acc[m][n], 0, 0, 0);
        }
        __syncthreads();
    }

    #pragma unroll
    for (int m = 0; m < 4; ++m) {
        #pragma unroll
        for (int r = 0; r < 4; ++r) {
            int gr = row0 + wr + m * 16 + lg * 4 + r;
            if (gr >= M) continue;
            #pragma unroll
            for (int n = 0; n < 4; ++n) {
                int gc = col0 + wc + n * 16 + lr;
                float v = acc[m][n][r];
                if (HAS_BIAS) v += bias[gc];
                storev(&C[(size_t)gr * ldc + gc], v);
            }
        }
    }
}

// ============ edge GEMM (BK=64) + fused logits, sorted-edge space ============
__global__ __launch_bounds__(256) void edge_mfma_logits(
    const __hip_bfloat16* __restrict__ ea,
    const __hip_bfloat16* __restrict__ WleT,
    const __hip_bfloat16* __restrict__ XL,
    const __hip_bfloat16* __restrict__ XR,
    const int* __restrict__ ssrc,
    const int* __restrict__ sdst,
    const float* __restrict__ att,
    float* __restrict__ logits,
    int E)
{
    __shared__ uint4 As4[1024];
    __shared__ uint4 Bs4[1024];
    __shared__ int srcs[128], dsts[128];
    const int t = threadIdx.x, lane = t & 63, w = t >> 6;
    const int wr = (w >> 1) * 64, wc = (w & 1) * 64;
    const int col0 = blockIdx.x * 128, row0 = blockIdx.y * 128;
    const int lr = lane & 15, lg = lane >> 4;
    const int srow8 = lane >> 3;
    const int sch   = (lane & 7) ^ srow8;
    const int rx = lr & 7;

    if (t < 128) {
        int ge = row0 + t;
        bool ok = ge < E;
        srcs[t] = ok ? ssrc[ge] : 0;
        dsts[t] = ok ? sdst[ge] : 0;
    }
    const __hip_bfloat16* ApL = ea + (size_t)(row0 + srow8) * 512 + sch * 8;
    const __hip_bfloat16* BpL = WleT + (size_t)(col0 + srow8) * 512 + sch * 8;
    __syncthreads();

    f32x4 acc[4][4];
    #pragma unroll
    for (int m = 0; m < 4; ++m)
        #pragma unroll
        for (int n = 0; n < 4; ++n) acc[m][n] = 0.f;

    for (int k0 = 0; k0 < 512; k0 += 64) {
        #pragma unroll
        for (int j = 0; j < 4; ++j) {
            int rb = (w + 4 * j) * 8;
            GLD16(ApL + (size_t)rb * 512 + k0, As4 + (w + 4 * j) * 64);
            GLD16(BpL + (size_t)rb * 512 + k0, Bs4 + (w + 4 * j) * 64);
        }
        __syncthreads();
        #pragma unroll
        for (int kk = 0; kk < 2; ++kk) {
            short8 af[4], bfrag[4];
            #pragma unroll
            for (int m = 0; m < 4; ++m) {
                int row = wr + m * 16 + lr;
                af[m] = *(const short8*)((const char*)As4 + row * 128 + (((kk * 4 + lg) ^ rx) << 4));
            }
            #pragma unroll
            for (int n = 0; n < 4; ++n) {
                int row = wc + n * 16 + lr;
                bfrag[n] = *(const short8*)((const char*)Bs4 + row * 128 + (((kk * 4 + lg) ^ rx) << 4));
            }
            #pragma unroll
            for (int m = 0; m < 4; ++m)
                #pragma unroll
                for (int n = 0; n < 4; ++n)
                    acc[m][n] = __builtin_amdgcn_mfma_f32_16x16x32_bf16(af[m], bfrag[n], acc[m][n], 0, 0, 0);
        }
        __syncthreads();
    }

    const int hh = col0 >> 9;
    float attv[4];
    #pragma unroll
    for (int n = 0; n < 4; ++n)
        attv[n] = att[hh * 512 + ((col0 + wc + n * 16 + lr) & 511)];
    float part[4][4];
    #pragma unroll
    for (int m = 0; m < 4; ++m)
        #pragma unroll
        for (int r = 0; r < 4; ++r) part[m][r] = 0.f;

    const int prt = (lane & 3) * 8;
    const int r0e = w * 16 + (lane >> 2);
    const int s0 = srcs[r0e], s1 = srcs[r0e + 64];
    const int d0 = dsts[r0e], d1 = dsts[r0e + 64];

    #pragma unroll
    for (int pair = 0; pair < 2; ++pair) {
        #pragma unroll
        for (int sp = 0; sp < 2; ++sp) {
            int ch = pair + sp * 2;
            int cc = col0 + ch * 32;
            GLD16(XL + (size_t)s0 * 2048 + cc + prt, As4 + sp * 512 + w * 64);
            GLD16(XL + (size_t)s1 * 2048 + cc + prt, As4 + sp * 512 + (w + 4) * 64);
            GLD16(XR + (size_t)d0 * 2048 + cc + prt, Bs4 + sp * 512 + w * 64);
            GLD16(XR + (size_t)d1 * 2048 + cc + prt, Bs4 + sp * 512 + (w + 4) * 64);
        }
        __syncthreads();
        #pragma unroll
        for (int sp = 0; sp < 2; ++sp) {
            int ch = pair + sp * 2;
            const char* AsB = (const char*)(As4 + sp * 512);
            const char* BsB = (const char*)(Bs4 + sp * 512);
            #pragma unroll
            for (int n = 0; n < 4; ++n) {
                if (((wc + n * 16) >> 5) != ch) continue;
                int colin = ((n & 1) << 4) + lr;
                #pragma unroll
                for (int m = 0; m < 4; ++m) {
                    #pragma unroll
                    for (int r = 0; r < 4; ++r) {
                        int row = wr + m * 16 + lg * 4 + r;
                        float xl = bfu(*(const unsigned short*)(AsB + row * 64 + colin * 2));
                        float xr = bfu(*(const unsigned short*)(BsB + row * 64 + colin * 2));
                        float mv = acc[m][n][r] + xl + xr;
                        part[m][r] += attv[n] * ((mv > 0.f) ? mv : 0.2f * mv);
                    }
                }
            }
        }
        __syncthreads();
    }
    #pragma unroll
    for (int m = 0; m < 4; ++m) {
        #pragma unroll
        for (int r = 0; r < 4; ++r) {
            float p = part[m][r];
            p += __shfl_xor(p, 1); p += __shfl_xor(p, 2);
            p += __shfl_xor(p, 4); p += __shfl_xor(p, 8);
            int ge = row0 + wr + m * 16 + lg * 4 + r;
            if (lr == 0 && ge < E) atomicAdd(&logits[ge * 4 + hh], p);
        }
    }
}

// ============ counting sort ============
__global__ __launch_bounds__(256) void count_dst(
    const int* __restrict__ ei, int* __restrict__ cnt, int E)
{
    int e = blockIdx.x * 256 + threadIdx.x;
    if (e < E) atomicAdd(&cnt[ei[E + e]], 1);
}

__global__ __launch_bounds__(1024) void scan_kernel(
    const int* __restrict__ cnt, int* __restrict__ offs, int N)
{
    __shared__ int wsum[16];
    __shared__ int stot;
    __shared__ int carry_s;
    int t = threadIdx.x, lane = t & 63, w = t >> 6;
    if (t == 0) carry_s = 0;
    __syncthreads();
    for (int base = 0; base < N; base += 1024) {
        int v = (base + t < N) ? cnt[base + t] : 0;
        int x = v;
        #pragma unroll
        for (int off = 1; off < 64; off <<= 1) {
            int y = __shfl_up(x, off);
            if (lane >= off) x += y;
        }
        if (lane == 63) wsum[w] = x;
        __syncthreads();
        if (w == 0 && lane < 16) {
            int v0 = wsum[lane];
            int s = v0;
            #pragma unroll
            for (int off = 1; off < 16; off <<= 1) {
                int y = __shfl_up(s, off);
                if (lane >= off) s += y;
            }
            wsum[lane] = s - v0;
            if (lane == 15) stot = s;
        }
        __syncthreads();
        if (base + t < N) offs[base + t] = carry_s + wsum[w] + x - v;
        __syncthreads();
        if (t == 0) carry_s += stot;
    }
    __syncthreads();
    if (t == 0) offs[N] = carry_s;
}

__global__ __launch_bounds__(256) void fill_elist(
    const int* __restrict__ ei, const int* __restrict__ offs,
    int* __restrict__ cnt2, int* __restrict__ elist,
    int* __restrict__ ssrc, int* __restrict__ sdst, int E)
{
    int e = blockIdx.x * 256 + threadIdx.x;
    if (e >= E) return;
    int d = ei[E + e];
    int p = offs[d] + atomicAdd(&cnt2[d], 1);
    elist[p] = e;
    ssrc[p] = ei[e];
    sdst[p] = d;
}

// ============ bias prep: bias2 = b_d1 + conv_bias@W_d1 ; blw = b_l@W_d1 ============
__global__ __launch_bounds__(256) void bias_init(
    const float* __restrict__ bd1, float* __restrict__ bias2, float* __restrict__ blw)
{
    int j = blockIdx.x * 256 + threadIdx.x;
    if (j < 512) { bias2[j] = bd1[j]; blw[j] = 0.f; }
}
__global__ __launch_bounds__(256) void bias_acc(
    const float* __restrict__ cb, const float* __restrict__ bl,
    const float* __restrict__ Wd1, float* __restrict__ bias2, float* __restrict__ blw)
{
    int g = blockIdx.x * 256 + threadIdx.x;   // 8192 threads: 512 j x 16 slices
    int j = g & 511, slice = g >> 9;
    float pa = 0.f, pb = 0.f;
    for (int k = slice * 128; k < slice * 128 + 128; ++k) {
        float wv = Wd1[(size_t)k * 512 + j];
        pa += cb[k] * wv;
        pb += bl[k] * wv;
    }
    atomicAdd(&bias2[j], pa);
    atomicAdd(&blw[j], pb);
}

// ============ fused output ============
__global__ __launch_bounds__(256) void gat_out(
    const __hip_bfloat16* __restrict__ Y,     // [N,4,512] bf16 (no bias terms)
    const int* __restrict__ ssrc, const int* __restrict__ offs,
    const float* __restrict__ logits,         // [E,4] sorted
    const float* __restrict__ bias2, const float* __restrict__ blw,
    const float* __restrict__ Wd2,
    const float* __restrict__ bd2,
    float* __restrict__ out, int N)
{
    __shared__ float wds[512 * 6];
    int t = threadIdx.x;
    for (int i = t; i < 512 * 6; i += 256) wds[i] = Wd2[i];
    __syncthreads();
    int w = t >> 6, lane = t & 63;
    int dst = blockIdx.x * 4 + w;
    if (dst >= N) return;
    int s = offs[dst], cntE = offs[dst + 1] - s;

    float den[4] = {0.f, 0.f, 0.f, 0.f};
    for (int i = 0; i < cntE; ++i) {
        #pragma unroll
        for (int h = 0; h < 4; ++h) den[h] += expf(logits[(s + i) * 4 + h]);
    }
    float acc[8] = {0.f, 0.f, 0.f, 0.f, 0.f, 0.f, 0.f, 0.f};
    for (int i = 0; i < cntE; ++i) {
        int p = s + i;
        int src = ssrc[p];
        #pragma unroll
        for (int h = 0; h < 4; ++h) {
            float al = expf(logits[p * 4 + h]) / (den[h] + 1e-16f);
            uint4 q = *(const uint4*)((const unsigned short*)Y
                        + ((size_t)src * 4 + h) * 512 + lane * 8);
            acc[0] += al * bfu((unsigned short)(q.x & 0xffff));
            acc[1] += al * bfu((unsigned short)(q.x >> 16));
            acc[2] += al * bfu((unsigned short)(q.y & 0xffff));
            acc[3] += al * bfu((unsigned short)(q.y >> 16));
            acc[4] += al * bfu((unsigned short)(q.z & 0xffff));
            acc[5] += al * bfu((unsigned short)(q.z >> 16));
            acc[6] += al * bfu((unsigned short)(q.w & 0xffff));
            acc[7] += al * bfu((unsigned short)(q.w >> 16));
        }
    }
    // sum(alpha)=1 per head only when edges exist; zero-degree nodes get no blw
    float gate = (cntE > 0) ? 1.f : 0.f;
    float p6[6] = {0.f, 0.f, 0.f, 0.f, 0.f, 0.f};
    #pragma unroll
    for (int j = 0; j < 8; ++j) {
        int c = lane * 8 + j;
        float u = fmaxf(acc[j] + bias2[c] + gate * blw[c], 0.f);
        #pragma unroll
        for (int jj = 0; jj < 6; ++jj) p6[jj] += u * wds[c * 6 + jj];
    }
    #pragma unroll
    for (int off = 32; off; off >>= 1)
        #pragma unroll
        for (int jj = 0; jj < 6; ++jj) p6[jj] += __shfl_down(p6[jj], off);
    if (lane == 0) {
        #pragma unroll
        for (int jj = 0; jj < 6; ++jj)
            out[(size_t)dst * 6 + jj] = 1.f / (1.f + expf(-(p6[jj] + bd2[jj])));
    }
}

extern "C" void kernel_launch(void* const* d_in, const int* in_sizes, int n_in,
                              void* d_out, int out_size, void* d_ws, size_t ws_size,
                              hipStream_t stream)
{
    const float* x         = (const float*)d_in[0];
    const float* edge_attr = (const float*)d_in[1];
    const int*   ei        = (const int*)d_in[2];
    const float* W_node = (const float*)d_in[3],  *b_node = (const float*)d_in[4];
    const float* W_edge = (const float*)d_in[5],  *b_edge = (const float*)d_in[6];
    const float* W_l    = (const float*)d_in[7],  *b_l    = (const float*)d_in[8];
    const float* W_r    = (const float*)d_in[9],  *b_r    = (const float*)d_in[10];
    const float* W_le   = (const float*)d_in[11];
    const float* att    = (const float*)d_in[12];
    const float* conv_bias = (const float*)d_in[13];
    const float* W_d1   = (const float*)d_in[14], *b_d1 = (const float*)d_in[15];
    const float* W_d2   = (const float*)d_in[16], *b_d2 = (const float*)d_in[17];
    float* out = (float*)d_out;

    const int N = in_sizes[0] / 7;   // 25000
    const int E = in_sizes[1] / 2;   // 50000
    const int MP = (N + 127) & ~127;
    const int EP = (E + 127) & ~127;

    // ---- workspace layout (~268 MB, same as round 10) ----
    // region0 (szR0) time-shares: h(1) -> ea -> h(2)
    // XL region temporarily hosts Wd1T/Wlbf during weight prep (before XL write)
    char* ws = (char*)d_ws;
    const size_t szR0 = (size_t)EP * 512 * 2;     // >= max(h 26MB, ea 51MB)
    const size_t szX  = (size_t)MP * 2048 * 2;
    const size_t szW  = (size_t)2048 * 512 * 2;   // 2 MB
    const size_t szlg = (size_t)E * 4 * 4;
    const size_t szI  = (((size_t)(N + 1) * 4) + 15) & ~(size_t)15;
    const size_t o_XL = szR0;
    const size_t o_XR = o_XL + szX;
    const size_t o_W  = o_XR + szX;                // WlT, WrT, WleT, WcombT
    const size_t o_lg = o_W + 4 * szW;
    const size_t o_b2 = o_lg + szlg;
    const size_t o_blw = o_b2 + 2048;
    const size_t o_bc = o_blw + 2048;
    const size_t o_cnt = o_bc + 4096 * 4;
    const size_t o_cnt2 = o_cnt + szI;
    const size_t o_off = o_cnt2 + szI;
    const size_t o_el = o_off + szI;
    const size_t o_ss = o_el + (size_t)E * 4;
    const size_t o_sd = o_ss + (size_t)E * 4;
    const size_t need = o_sd + (size_t)E * 4;
    if (ws_size < need) return;   // clean diagnostic failure if ws too small

    __hip_bfloat16* h   = (__hip_bfloat16*)ws;      // region0
    __hip_bfloat16* ea  = (__hip_bfloat16*)ws;      // region0 (overlays h)
    __hip_bfloat16* XL  = (__hip_bfloat16*)(ws + o_XL);
    __hip_bfloat16* XR  = (__hip_bfloat16*)(ws + o_XR);
    __hip_bfloat16* Y   = XR;                       // overlays XR after logits
    __hip_bfloat16* WlT = (__hip_bfloat16*)(ws + o_W);
    __hip_bfloat16* WrT = WlT + szW / 2;
    __hip_bfloat16* WleT= WrT + szW / 2;
    __hip_bfloat16* WcombT = WleT + szW / 2;        // [2048,512]
    // transient (XL region, dead before XL is written):
    __hip_bfloat16* Wd1T_t = (__hip_bfloat16*)(ws + o_XL);           // [512,2048]
    __hip_bfloat16* Wlbf_t = (__hip_bfloat16*)(ws + o_XL + szW);     // [512,2048]
    float* logits = (float*)(ws + o_lg);
    float* bias2  = (float*)(ws + o_b2);
    float* blw    = (float*)(ws + o_blw);
    float* bcat   = (float*)(ws + o_bc);
    int* cnt   = (int*)(ws + o_cnt);
    int* cnt2  = (int*)(ws + o_cnt2);
    int* offs  = (int*)(ws + o_off);
    int* elist = (int*)(ws + o_el);
    int* ssrc  = (int*)(ws + o_ss);
    int* sdst  = (int*)(ws + o_sd);

    hipMemsetAsync(logits, 0, szlg, stream);
    hipMemsetAsync(cnt, 0, szI, stream);
    hipMemsetAsync(cnt2, 0, szI, stream);
    hipMemcpyAsync(bcat, b_l, 2048 * 4, hipMemcpyDeviceToDevice, stream);
    hipMemcpyAsync(bcat + 2048, b_r, 2048 * 4, hipMemcpyDeviceToDevice, stream);

    // ---- weight prep ----
    dim3 gT(512 / 32, 2048 / 32);
    transpose_bf16<<<gT, 256, 0, stream>>>(W_l,  WlT, 512, 2048);
    transpose_bf16<<<gT, 256, 0, stream>>>(W_r,  WrT, 512, 2048);
    transpose_bf16<<<gT, 256, 0, stream>>>(W_le, WleT, 512, 2048);
    dim3 gT2(2048 / 32, 512 / 32);
    transpose_bf16<<<gT2, 256, 0, stream>>>(W_d1, Wd1T_t, 2048, 512);
    cast_bf16<<<(512 * 2048 + 255) / 256, 256, 0, stream>>>(W_l, Wlbf_t, 512 * 2048);

    // WcombT[hz*512+j, k] = sum_c W_d1[hz*512+c, j] * W_l[k, hz*512+c]
    dim3 gWc(512 / 128, 512 / 128, 4);
    mfma_gemm<__hip_bfloat16, false><<<gWc, 256, 0, stream>>>(
        Wd1T_t, 2048, 512, Wlbf_t, 2048, 512, nullptr, 0,
        WcombT, 512, (long)512 * 512, 512, 512);

    bias_init<<<2, 256, 0, stream>>>(b_d1, bias2, blw);
    bias_acc<<<32, 256, 0, stream>>>(conv_bias, b_l, W_d1, bias2, blw);

    // ---- counting sort of edges by dst ----
    count_dst<<<(E + 255) / 256, 256, 0, stream>>>(ei, cnt, E);
    scan_kernel<<<1, 1024, 0, stream>>>(cnt, offs, N);
    fill_elist<<<(E + 255) / 256, 256, 0, stream>>>(ei, offs, cnt2, elist, ssrc, sdst, E);

    // ---- h(1) -> XL/XR ----
    encode_nodes<<<(N * 512 + 255) / 256, 256, 0, stream>>>(x, W_node, b_node, h, N);

    const int MB = MP / 128;
    dim3 gNode(2048 / 128, MB, 2);
    mfma_gemm<__hip_bfloat16, true><<<gNode, 256, 0, stream>>>(
        h, 512, 0, WlT, 512, (long)2048 * 512, bcat, 2048,
        XL, 2048, (long)MP * 2048, N, 512);

    // ---- ea (overlays h) -> edge logits ----
    encode_edges_sorted<<<(E * 512 + 255) / 256, 256, 0, stream>>>(
        edge_attr, elist, W_edge, b_edge, ea, E);

    dim3 gE(16, EP / 128);
    edge_mfma_logits<<<gE, 256, 0, stream>>>(ea, WleT, XL, XR, ssrc, sdst, att, logits, E);

    // ---- h(2) (overlays ea) -> Y = h @ WcombT (Y overlays dead XR) ----
    encode_nodes<<<(N * 512 + 255) / 256, 256, 0, stream>>>(x, W_node, b_node, h, N);

    dim3 gY(2048 / 128, MB);
    mfma_gemm<__hip_bfloat16, false><<<gY, 256, 0, stream>>>(
        h, 512, 0, WcombT, 512, 0, nullptr, 0, Y, 2048, 0, N, 512);

    gat_out<<<(N + 3) / 4, 256, 0, stream>>>(Y, ssrc, offs, logits,
                                             bias2, blw, W_d2, b_d2, out, N);
}